// Round 1
// baseline (485.641 us; speedup 1.0000x reference)
//
#include <hip/hip_runtime.h>
#include <hip/hip_bf16.h>

typedef short bf16x8 __attribute__((ext_vector_type(8)));
typedef float f32x4 __attribute__((ext_vector_type(4)));
typedef unsigned short ushort8v __attribute__((ext_vector_type(8)));

__device__ __forceinline__ unsigned short f2bf(float f) {
  unsigned u = __builtin_bit_cast(unsigned, f);
  u += 0x7fffu + ((u >> 16) & 1u);   // round-to-nearest-even (no NaN inputs here)
  return (unsigned short)(u >> 16);
}

__device__ __forceinline__ void gload_lds16(const unsigned short* g, unsigned short* l) {
  __builtin_amdgcn_global_load_lds((const __attribute__((address_space(1))) void*)g,
                                   (__attribute__((address_space(3))) void*)l, 16, 0, 0);
}

// ---------------- cast x (fp32) -> bf16 ----------------
__global__ __launch_bounds__(256) void cast_x_kernel(const float* __restrict__ in,
                                                     unsigned short* __restrict__ out,
                                                     int n8) {
  int i = blockIdx.x * 256 + threadIdx.x;
  if (i >= n8) return;
  const float4* p = (const float4*)in + (size_t)i * 2;
  float4 a = p[0], b = p[1];
  ushort8v v;
  v[0] = f2bf(a.x); v[1] = f2bf(a.y); v[2] = f2bf(a.z); v[3] = f2bf(a.w);
  v[4] = f2bf(b.x); v[5] = f2bf(b.y); v[6] = f2bf(b.z); v[7] = f2bf(b.w);
  *((ushort8v*)out + i) = v;
}

// ---------------- W_eff = W + scale * B@A  -> bf16 ----------------
__global__ __launch_bounds__(256) void make_weff_kernel(const float* __restrict__ W,
                                                        const float* __restrict__ A,
                                                        const float* __restrict__ Bm,
                                                        unsigned short* __restrict__ out,
                                                        float scale, int K, int R, int total8) {
  int idx = blockIdx.x * 256 + threadIdx.x;
  if (idx >= total8) return;
  int perRow = K >> 3;
  int n = idx / perRow;
  int d0 = (idx - n * perRow) << 3;
  const float4* wp = (const float4*)(W + (size_t)n * K + d0);
  float4 w0 = wp[0], w1 = wp[1];
  float acc[8] = {w0.x, w0.y, w0.z, w0.w, w1.x, w1.y, w1.z, w1.w};
#pragma unroll 4
  for (int r = 0; r < R; ++r) {
    float c = Bm[(size_t)n * R + r] * scale;
    const float4* ap = (const float4*)(A + (size_t)r * K + d0);
    float4 a0 = ap[0], a1 = ap[1];
    acc[0] += c * a0.x; acc[1] += c * a0.y; acc[2] += c * a0.z; acc[3] += c * a0.w;
    acc[4] += c * a1.x; acc[5] += c * a1.y; acc[6] += c * a1.z; acc[7] += c * a1.w;
  }
  ushort8v v;
#pragma unroll
  for (int j = 0; j < 8; ++j) v[j] = f2bf(acc[j]);
  *((ushort8v*)out + idx) = v;
}

// ---------------- bf16 GEMM: C[M][N] = Xb[M][K] @ Wb[N][K]^T + bias ----------------
// m97 structure: 128x128 tile, BK=32, 4 waves each 64x64, 16x16x32 MFMA,
// global_load_lds width-16 staging (linear LDS), 2-barrier K-loop, XCD swizzle.
__global__ __launch_bounds__(256) void gemm_bt_bias(const unsigned short* __restrict__ Xb,
                                                    const unsigned short* __restrict__ Wb,
                                                    const float* __restrict__ bias,
                                                    float* __restrict__ C,
                                                    int M, int N, int K) {
  __shared__ unsigned short sA[128 * 32];
  __shared__ unsigned short sB[128 * 32];
  const int t = threadIdx.x;
  const int wave = t >> 6, lane = t & 63;
  const int NT = N >> 7;
  const int nwg = gridDim.x;
  int bid = blockIdx.x;
  if ((nwg & 7) == 0) {                 // bijective XCD swizzle
    bid = (bid & 7) * (nwg >> 3) + (bid >> 3);
  }
  const int tm = bid / NT, tn = bid % NT;
  const int m0 = tm << 7, n0 = tn << 7;
  const int wr = wave >> 1, wc = wave & 1;

  f32x4 acc[4][4];
#pragma unroll
  for (int m = 0; m < 4; ++m)
#pragma unroll
    for (int n = 0; n < 4; ++n) acc[m][n] = (f32x4){0.f, 0.f, 0.f, 0.f};

  // staging: chunk c (of 8 bf16) -> tile row c>>2, col (c&3)*8; LDS byte = c*16.
  const unsigned short* gA0 = Xb + (size_t)(m0 + (t >> 2)) * K + (t & 3) * 8;
  const unsigned short* gA1 = Xb + (size_t)(m0 + 64 + (t >> 2)) * K + (t & 3) * 8;
  const unsigned short* gB0 = Wb + (size_t)(n0 + (t >> 2)) * K + (t & 3) * 8;
  const unsigned short* gB1 = Wb + (size_t)(n0 + 64 + (t >> 2)) * K + (t & 3) * 8;
  unsigned short* lA0 = sA + (size_t)(wave * 64) * 8;          // *16 bytes = *8 ushorts
  unsigned short* lA1 = sA + (size_t)(256 + wave * 64) * 8;
  unsigned short* lB0 = sB + (size_t)(wave * 64) * 8;
  unsigned short* lB1 = sB + (size_t)(256 + wave * 64) * 8;

  const int rrow = lane & 15;
  const int rk = (lane >> 4) * 8;

  for (int k0 = 0; k0 < K; k0 += 32) {
    gload_lds16(gA0 + k0, lA0);
    gload_lds16(gA1 + k0, lA1);
    gload_lds16(gB0 + k0, lB0);
    gload_lds16(gB1 + k0, lB1);
    __syncthreads();   // drains vmcnt -> LDS tiles ready

    bf16x8 af[4], bfr[4];
#pragma unroll
    for (int m = 0; m < 4; ++m)
      af[m] = *(const bf16x8*)&sA[(size_t)(wr * 64 + m * 16 + rrow) * 32 + rk];
#pragma unroll
    for (int n = 0; n < 4; ++n)
      bfr[n] = *(const bf16x8*)&sB[(size_t)(wc * 64 + n * 16 + rrow) * 32 + rk];
#pragma unroll
    for (int m = 0; m < 4; ++m)
#pragma unroll
      for (int n = 0; n < 4; ++n)
        acc[m][n] = __builtin_amdgcn_mfma_f32_16x16x32_bf16(af[m], bfr[n], acc[m][n], 0, 0, 0);

    __syncthreads();   // all reads done before next-tile overwrite
  }

  // epilogue: D lane map (16x16x32): col = lane&15, row = (lane>>4)*4 + reg
  const int crow0 = (lane >> 4) * 2 * 2;  // (lane>>4)*4
  const int ccol = lane & 15;
#pragma unroll
  for (int n = 0; n < 4; ++n) {
    int col = n0 + wc * 64 + n * 16 + ccol;
    float bv = bias[col];
#pragma unroll
    for (int m = 0; m < 4; ++m) {
      int row = m0 + wr * 64 + m * 16 + crow0;
      float* cp = C + (size_t)row * N + col;
#pragma unroll
      for (int r = 0; r < 4; ++r) cp[(size_t)r * N] = acc[m][n][r] + bv;
    }
  }
}

// ---------------- fallback (no workspace for bf16 copies): fp32 path ----------------
__global__ __launch_bounds__(64) void lora_h_kernel(const float* __restrict__ x,
                                                    const float* __restrict__ A,
                                                    float* __restrict__ h,
                                                    float scale, int K, int R) {
  int m = blockIdx.x, lane = threadIdx.x;
  float acc[16];
#pragma unroll
  for (int r = 0; r < 16; ++r) acc[r] = 0.f;
  for (int d = lane; d < K; d += 64) {
    float xv = x[(size_t)m * K + d];
    for (int r = 0; r < R; ++r) acc[r] += xv * A[(size_t)r * K + d];
  }
  for (int off = 32; off; off >>= 1)
    for (int r = 0; r < R; ++r) acc[r] += __shfl_down(acc[r], off);
  if (lane == 0)
    for (int r = 0; r < R; ++r) h[(size_t)m * R + r] = acc[r] * scale;
}

__global__ __launch_bounds__(256) void fgemm_fallback(const float* __restrict__ X,
                                                      const float* __restrict__ W,
                                                      const float* __restrict__ Bm,
                                                      const float* __restrict__ bias,
                                                      const float* __restrict__ h,
                                                      float* __restrict__ C,
                                                      int M, int N, int K, int R) {
  __shared__ float sX[64][20];
  __shared__ float sW[64][20];
  int nt = N >> 6;
  int bx = blockIdx.x % nt, by = blockIdx.x / nt;
  int m0 = by << 6, n0 = bx << 6;
  int t = threadIdx.x;
  int tx = t & 15, ty = t >> 4;
  float acc[4][4] = {};
  int lr = t >> 2, lc = (t & 3) << 2;
  for (int k0 = 0; k0 < K; k0 += 16) {
    *(float4*)&sX[lr][lc] = *(const float4*)&X[(size_t)(m0 + lr) * K + k0 + lc];
    *(float4*)&sW[lr][lc] = *(const float4*)&W[(size_t)(n0 + lr) * K + k0 + lc];
    __syncthreads();
#pragma unroll
    for (int kk = 0; kk < 16; ++kk) {
      float a[4], b[4];
#pragma unroll
      for (int i = 0; i < 4; ++i) a[i] = sX[ty * 4 + i][kk];
#pragma unroll
      for (int j = 0; j < 4; ++j) b[j] = sW[tx * 4 + j][kk];
#pragma unroll
      for (int i = 0; i < 4; ++i)
#pragma unroll
        for (int j = 0; j < 4; ++j) acc[i][j] += a[i] * b[j];
    }
    __syncthreads();
  }
#pragma unroll
  for (int i = 0; i < 4; ++i) {
    int row = m0 + ty * 4 + i;
#pragma unroll
    for (int j = 0; j < 4; ++j) {
      int col = n0 + tx * 4 + j;
      float lo = 0.f;
      for (int r = 0; r < R; ++r) lo += h[(size_t)row * R + r] * Bm[(size_t)col * R + r];
      C[(size_t)row * N + col] = acc[i][j] + bias[col] + lo;
    }
  }
}

extern "C" void kernel_launch(void* const* d_in, const int* in_sizes, int n_in,
                              void* d_out, int out_size, void* d_ws, size_t ws_size,
                              hipStream_t stream) {
  const float* x    = (const float*)d_in[0];
  const float* W    = (const float*)d_in[1];
  const float* A    = (const float*)d_in[2];
  const float* Bm   = (const float*)d_in[3];
  const float* bias = (const float*)d_in[4];
  float* out = (float*)d_out;

  const int N = in_sizes[4];            // D_out = 4096
  const int R = in_sizes[3] / N;        // 16
  const int K = in_sizes[2] / R;        // D_in = 4096
  const int M = in_sizes[0] / K;        // B*S = 8192
  const float scale = 16.0f / (float)R; // LORA_ALPHA / rank

  const size_t xbytes = (size_t)M * K * 2;
  const size_t wbytes = (size_t)N * K * 2;
  const bool fast = (ws_size >= xbytes + wbytes) &&
                    (M % 128 == 0) && (N % 128 == 0) && (K % 32 == 0);

  if (fast) {
    unsigned short* xb = (unsigned short*)d_ws;
    unsigned short* wb = (unsigned short*)((char*)d_ws + xbytes);
    int n8 = M * K / 8;
    cast_x_kernel<<<dim3((n8 + 255) / 256), dim3(256), 0, stream>>>(x, xb, n8);
    int t8 = N * K / 8;
    make_weff_kernel<<<dim3((t8 + 255) / 256), dim3(256), 0, stream>>>(W, A, Bm, wb, scale, K, R, t8);
    int grid = (M / 128) * (N / 128);
    gemm_bt_bias<<<dim3(grid), dim3(256), 0, stream>>>(xb, wb, bias, out, M, N, K);
  } else {
    float* h = (float*)d_ws;  // M*R fp32 = 512 KB
    lora_h_kernel<<<dim3(M), dim3(64), 0, stream>>>(x, A, h, scale, K, R);
    int grid = (M / 64) * (N / 64);
    fgemm_fallback<<<dim3(grid), dim3(256), 0, stream>>>(x, W, Bm, bias, h, out, M, N, K, R);
  }
}

// Round 3
// 358.560 us; speedup vs baseline: 1.3544x; 1.3544x over previous
//
#include <hip/hip_runtime.h>
#include <hip/hip_bf16.h>

typedef short bf16x8 __attribute__((ext_vector_type(8)));
typedef float f32x4 __attribute__((ext_vector_type(4)));
typedef unsigned short ushort8v __attribute__((ext_vector_type(8)));

#define VMWAIT(n) asm volatile("s_waitcnt vmcnt(" #n ")" ::: "memory")
#define SBAR() asm volatile("s_barrier" ::: "memory")

__device__ __forceinline__ unsigned short f2bf(float f) {
  unsigned u = __builtin_bit_cast(unsigned, f);
  u += 0x7fffu + ((u >> 16) & 1u);   // round-to-nearest-even
  return (unsigned short)(u >> 16);
}

__device__ __forceinline__ void gload_lds16(const unsigned short* g, unsigned short* l) {
  __builtin_amdgcn_global_load_lds((const __attribute__((address_space(1))) void*)g,
                                   (__attribute__((address_space(3))) void*)l, 16, 0, 0);
}

// ---------------- cast x (fp32) -> bf16 ----------------
__global__ __launch_bounds__(256) void cast_x_kernel(const float* __restrict__ in,
                                                     unsigned short* __restrict__ out,
                                                     int n8) {
  int i = blockIdx.x * 256 + threadIdx.x;
  if (i >= n8) return;
  const float4* p = (const float4*)in + (size_t)i * 2;
  float4 a = p[0], b = p[1];
  ushort8v v;
  v[0] = f2bf(a.x); v[1] = f2bf(a.y); v[2] = f2bf(a.z); v[3] = f2bf(a.w);
  v[4] = f2bf(b.x); v[5] = f2bf(b.y); v[6] = f2bf(b.z); v[7] = f2bf(b.w);
  *((ushort8v*)out + i) = v;
}

// ---------------- W_eff = W + scale * B@A  -> bf16 ----------------
__global__ __launch_bounds__(256) void make_weff_kernel(const float* __restrict__ W,
                                                        const float* __restrict__ A,
                                                        const float* __restrict__ Bm,
                                                        unsigned short* __restrict__ out,
                                                        float scale, int K, int R, int total8) {
  int idx = blockIdx.x * 256 + threadIdx.x;
  if (idx >= total8) return;
  int perRow = K >> 3;
  int n = idx / perRow;
  int d0 = (idx - n * perRow) << 3;
  const float4* wp = (const float4*)(W + (size_t)n * K + d0);
  float4 w0 = wp[0], w1 = wp[1];
  float acc[8] = {w0.x, w0.y, w0.z, w0.w, w1.x, w1.y, w1.z, w1.w};
#pragma unroll 4
  for (int r = 0; r < R; ++r) {
    float c = Bm[(size_t)n * R + r] * scale;
    const float4* ap = (const float4*)(A + (size_t)r * K + d0);
    float4 a0 = ap[0], a1 = ap[1];
    acc[0] += c * a0.x; acc[1] += c * a0.y; acc[2] += c * a0.z; acc[3] += c * a0.w;
    acc[4] += c * a1.x; acc[5] += c * a1.y; acc[6] += c * a1.z; acc[7] += c * a1.w;
  }
  ushort8v v;
#pragma unroll
  for (int j = 0; j < 8; ++j) v[j] = f2bf(acc[j]);
  *((ushort8v*)out + idx) = v;
}

// ---------------- 256x256 deep-pipeline bf16 GEMM: C = Xb @ Wb^T + bias --------
// BK=32, 8 waves (2x4) each owning 128x64, 4 LDS buffers staged 3 K-tiles ahead,
// counted vmcnt (12/8/4/0), raw s_barrier, chunk-XOR LDS swizzle, setprio MFMA.
// Buffer layout (bytes): A rows 0..255 at [0, 16384); B rows 0..255 at [16384, 32768).
__global__ __launch_bounds__(512, 2) void gemm256_bt_bias(const unsigned short* __restrict__ Xb,
                                                          const unsigned short* __restrict__ Wb,
                                                          const float* __restrict__ bias,
                                                          float* __restrict__ C,
                                                          int M, int N, int K) {
  __shared__ __align__(16) unsigned short lds[4][16384]; // [buf][ A:0..8191 | B:8192..16383 ] (ushorts)
  const int t = threadIdx.x;
  const int wave = t >> 6, lane = t & 63;
  const int fr = lane & 15, kc = lane >> 4;          // fragment row, k-chunk (16B)
  const int wr = wave >> 2, wc = wave & 3;

  const int NTn = N >> 8;
  const int nwg = gridDim.x;
  int bid = blockIdx.x;
  if ((nwg & 7) == 0) bid = (bid & 7) * (nwg >> 3) + (bid >> 3);  // XCD swizzle
  const int tm = bid / NTn, tn = bid % NTn;
  const int m0 = tm << 8, n0 = tn << 8;

  // ---- staging (global -> LDS, linear dest, pre-swizzled global chunk) ----
  // LDS[row][lc] = G[row][lc ^ ((row>>1)&3)]; lane t: row=t>>2, lc=t&3.
  const int srow = t >> 2;                           // 0..127
  const int gch  = (t & 3) ^ ((t >> 3) & 3);
  const unsigned short* gA0 = Xb + (size_t)(m0 + srow) * K + gch * 8;
  const unsigned short* gA1 = gA0 + (size_t)128 * K;
  const unsigned short* gB0 = Wb + (size_t)(n0 + srow) * K + gch * 8;
  const unsigned short* gB1 = gB0 + (size_t)128 * K;
  const int stA0 = wave * 512;                       // ushort offsets in buffer
  const int stA1 = 4096 + wave * 512;
  const int stB0 = 8192 + wave * 512;
  const int stB1 = 12288 + wave * 512;

  // ---- per-lane read byte-offsets within a buffer (tile-independent) ----
  int offA[8], offB[4];
#pragma unroll
  for (int m = 0; m < 8; ++m) {
    int row = wr * 128 + m * 16 + fr;
    offA[m] = row * 64 + (((kc ^ (row >> 1)) & 3) << 4);
  }
#pragma unroll
  for (int n = 0; n < 4; ++n) {
    int row = wc * 64 + n * 16 + fr;
    offB[n] = 16384 + row * 64 + (((kc ^ (row >> 1)) & 3) << 4);  // B region at BYTE 16384
  }

  f32x4 acc[8][4];
#pragma unroll
  for (int m = 0; m < 8; ++m)
#pragma unroll
    for (int n = 0; n < 4; ++n) acc[m][n] = (f32x4){0.f, 0.f, 0.f, 0.f};

  const int NT = K >> 5;

#define STAGE(tt) do {                                   \
    unsigned short* sb_ = &lds[(tt) & 3][0];             \
    const int ko_ = (tt) * 32;                           \
    gload_lds16(gA0 + ko_, sb_ + stA0);                  \
    gload_lds16(gA1 + ko_, sb_ + stA1);                  \
    gload_lds16(gB0 + ko_, sb_ + stB0);                  \
    gload_lds16(gB1 + ko_, sb_ + stB1);                  \
  } while (0)

#define COMPUTE(tt) do {                                                          \
    const char* p_ = (const char*)&lds[(tt) & 3][0];                              \
    bf16x8 av_[4], bv_[4];                                                        \
    _Pragma("unroll") for (int n = 0; n < 4; ++n)                                 \
      bv_[n] = *(const bf16x8*)(p_ + offB[n]);                                    \
    _Pragma("unroll") for (int m = 0; m < 4; ++m)                                 \
      av_[m] = *(const bf16x8*)(p_ + offA[m]);                                    \
    __builtin_amdgcn_s_setprio(1);                                                \
    _Pragma("unroll") for (int m = 0; m < 4; ++m)                                 \
      _Pragma("unroll") for (int n = 0; n < 4; ++n)                               \
        acc[m][n] = __builtin_amdgcn_mfma_f32_16x16x32_bf16(av_[m], bv_[n], acc[m][n], 0, 0, 0); \
    __builtin_amdgcn_s_setprio(0);                                                \
    _Pragma("unroll") for (int m = 0; m < 4; ++m)                                 \
      av_[m] = *(const bf16x8*)(p_ + offA[4 + m]);                                \
    __builtin_amdgcn_s_setprio(1);                                                \
    _Pragma("unroll") for (int m = 0; m < 4; ++m)                                 \
      _Pragma("unroll") for (int n = 0; n < 4; ++n)                               \
        acc[4 + m][n] = __builtin_amdgcn_mfma_f32_16x16x32_bf16(av_[m], bv_[n], acc[4 + m][n], 0, 0, 0); \
    __builtin_amdgcn_s_setprio(0);                                                \
  } while (0)

  STAGE(0); STAGE(1); STAGE(2);
  int tt = 0;
  for (; tt < NT - 3; ++tt) {
    STAGE(tt + 3);          // buffer (tt+3)&3 was freed by barrier at end of tt-1
    VMWAIT(12);             // oldest 4 loads (tile tt) have landed
    SBAR();                 // all waves' tile-tt data visible
    COMPUTE(tt);
    SBAR();                 // tile-tt reads done -> its buffer reusable
  }
  VMWAIT(8);  SBAR(); COMPUTE(NT - 3); SBAR();
  VMWAIT(4);  SBAR(); COMPUTE(NT - 2); SBAR();
  VMWAIT(0);  SBAR(); COMPUTE(NT - 1);

  // ---- epilogue: D map col = lane&15, row = (lane>>4)*4 + reg ----
  const int crow = (lane >> 4) * 4;
  const int ccol = lane & 15;
#pragma unroll
  for (int n = 0; n < 4; ++n) {
    int col = n0 + wc * 64 + n * 16 + ccol;
    float bv = bias[col];
#pragma unroll
    for (int m = 0; m < 8; ++m) {
      int row = m0 + wr * 128 + m * 16 + crow;
      float* cp = C + (size_t)row * N + col;
#pragma unroll
      for (int r = 0; r < 4; ++r) cp[(size_t)r * N] = acc[m][n][r] + bv;
    }
  }
#undef STAGE
#undef COMPUTE
}

// ---------------- 128x128 m97-structure fallback GEMM ----------------
__global__ __launch_bounds__(256) void gemm_bt_bias(const unsigned short* __restrict__ Xb,
                                                    const unsigned short* __restrict__ Wb,
                                                    const float* __restrict__ bias,
                                                    float* __restrict__ C,
                                                    int M, int N, int K) {
  __shared__ unsigned short sA[128 * 32];
  __shared__ unsigned short sB[128 * 32];
  const int t = threadIdx.x;
  const int wave = t >> 6, lane = t & 63;
  const int NT = N >> 7;
  const int nwg = gridDim.x;
  int bid = blockIdx.x;
  if ((nwg & 7) == 0) bid = (bid & 7) * (nwg >> 3) + (bid >> 3);
  const int tm = bid / NT, tn = bid % NT;
  const int m0 = tm << 7, n0 = tn << 7;
  const int wr = wave >> 1, wc = wave & 1;

  f32x4 acc[4][4];
#pragma unroll
  for (int m = 0; m < 4; ++m)
#pragma unroll
    for (int n = 0; n < 4; ++n) acc[m][n] = (f32x4){0.f, 0.f, 0.f, 0.f};

  const unsigned short* gA0 = Xb + (size_t)(m0 + (t >> 2)) * K + (t & 3) * 8;
  const unsigned short* gA1 = Xb + (size_t)(m0 + 64 + (t >> 2)) * K + (t & 3) * 8;
  const unsigned short* gB0 = Wb + (size_t)(n0 + (t >> 2)) * K + (t & 3) * 8;
  const unsigned short* gB1 = Wb + (size_t)(n0 + 64 + (t >> 2)) * K + (t & 3) * 8;
  unsigned short* lA0 = sA + (size_t)(wave * 64) * 8;
  unsigned short* lA1 = sA + (size_t)(256 + wave * 64) * 8;
  unsigned short* lB0 = sB + (size_t)(wave * 64) * 8;
  unsigned short* lB1 = sB + (size_t)(256 + wave * 64) * 8;

  const int rrow = lane & 15;
  const int rk = (lane >> 4) * 8;

  for (int k0 = 0; k0 < K; k0 += 32) {
    gload_lds16(gA0 + k0, lA0);
    gload_lds16(gA1 + k0, lA1);
    gload_lds16(gB0 + k0, lB0);
    gload_lds16(gB1 + k0, lB1);
    __syncthreads();
    bf16x8 af[4], bfr[4];
#pragma unroll
    for (int m = 0; m < 4; ++m)
      af[m] = *(const bf16x8*)&sA[(size_t)(wr * 64 + m * 16 + rrow) * 32 + rk];
#pragma unroll
    for (int n = 0; n < 4; ++n)
      bfr[n] = *(const bf16x8*)&sB[(size_t)(wc * 64 + n * 16 + rrow) * 32 + rk];
#pragma unroll
    for (int m = 0; m < 4; ++m)
#pragma unroll
      for (int n = 0; n < 4; ++n)
        acc[m][n] = __builtin_amdgcn_mfma_f32_16x16x32_bf16(af[m], bfr[n], acc[m][n], 0, 0, 0);
    __syncthreads();
  }
  const int crow0 = (lane >> 4) * 4;
  const int ccol = lane & 15;
#pragma unroll
  for (int n = 0; n < 4; ++n) {
    int col = n0 + wc * 64 + n * 16 + ccol;
    float bv = bias[col];
#pragma unroll
    for (int m = 0; m < 4; ++m) {
      int row = m0 + wr * 64 + m * 16 + crow0;
      float* cp = C + (size_t)row * N + col;
#pragma unroll
      for (int r = 0; r < 4; ++r) cp[(size_t)r * N] = acc[m][n][r] + bv;
    }
  }
}

// ---------------- fp32 fallback ----------------
__global__ __launch_bounds__(64) void lora_h_kernel(const float* __restrict__ x,
                                                    const float* __restrict__ A,
                                                    float* __restrict__ h,
                                                    float scale, int K, int R) {
  int m = blockIdx.x, lane = threadIdx.x;
  float acc[16];
#pragma unroll
  for (int r = 0; r < 16; ++r) acc[r] = 0.f;
  for (int d = lane; d < K; d += 64) {
    float xv = x[(size_t)m * K + d];
    for (int r = 0; r < R; ++r) acc[r] += xv * A[(size_t)r * K + d];
  }
  for (int off = 32; off; off >>= 1)
    for (int r = 0; r < R; ++r) acc[r] += __shfl_down(acc[r], off);
  if (lane == 0)
    for (int r = 0; r < R; ++r) h[(size_t)m * R + r] = acc[r] * scale;
}

__global__ __launch_bounds__(256) void fgemm_fallback(const float* __restrict__ X,
                                                      const float* __restrict__ W,
                                                      const float* __restrict__ Bm,
                                                      const float* __restrict__ bias,
                                                      const float* __restrict__ h,
                                                      float* __restrict__ C,
                                                      int M, int N, int K, int R) {
  __shared__ float sX[64][20];
  __shared__ float sW[64][20];
  int nt = N >> 6;
  int bx = blockIdx.x % nt, by = blockIdx.x / nt;
  int m0 = by << 6, n0 = bx << 6;
  int t = threadIdx.x;
  int tx = t & 15, ty = t >> 4;
  float acc[4][4] = {};
  int lr = t >> 2, lc = (t & 3) << 2;
  for (int k0 = 0; k0 < K; k0 += 16) {
    *(float4*)&sX[lr][lc] = *(const float4*)&X[(size_t)(m0 + lr) * K + k0 + lc];
    *(float4*)&sW[lr][lc] = *(const float4*)&W[(size_t)(n0 + lr) * K + k0 + lc];
    __syncthreads();
#pragma unroll
    for (int kk = 0; kk < 16; ++kk) {
      float a[4], b[4];
#pragma unroll
      for (int i = 0; i < 4; ++i) a[i] = sX[ty * 4 + i][kk];
#pragma unroll
      for (int j = 0; j < 4; ++j) b[j] = sW[tx * 4 + j][kk];
#pragma unroll
      for (int i = 0; i < 4; ++i)
#pragma unroll
        for (int j = 0; j < 4; ++j) acc[i][j] += a[i] * b[j];
    }
    __syncthreads();
  }
#pragma unroll
  for (int i = 0; i < 4; ++i) {
    int row = m0 + ty * 4 + i;
#pragma unroll
    for (int j = 0; j < 4; ++j) {
      int col = n0 + tx * 4 + j;
      float lo = 0.f;
      for (int r = 0; r < R; ++r) lo += h[(size_t)row * R + r] * Bm[(size_t)col * R + r];
      C[(size_t)row * N + col] = acc[i][j] + bias[col] + lo;
    }
  }
}

extern "C" void kernel_launch(void* const* d_in, const int* in_sizes, int n_in,
                              void* d_out, int out_size, void* d_ws, size_t ws_size,
                              hipStream_t stream) {
  const float* x    = (const float*)d_in[0];
  const float* W    = (const float*)d_in[1];
  const float* A    = (const float*)d_in[2];
  const float* Bm   = (const float*)d_in[3];
  const float* bias = (const float*)d_in[4];
  float* out = (float*)d_out;

  const int N = in_sizes[4];
  const int R = in_sizes[3] / N;
  const int K = in_sizes[2] / R;
  const int M = in_sizes[0] / K;
  const float scale = 16.0f / (float)R;

  const size_t xbytes = (size_t)M * K * 2;
  const size_t wbytes = (size_t)N * K * 2;
  const bool ws_ok = (ws_size >= xbytes + wbytes);
  const bool fast256 = ws_ok && (M % 256 == 0) && (N % 256 == 0) && (K % 32 == 0) && (K >= 128);
  const bool fast128 = ws_ok && (M % 128 == 0) && (N % 128 == 0) && (K % 32 == 0);

  if (fast256 || fast128) {
    unsigned short* xb = (unsigned short*)d_ws;
    unsigned short* wb = (unsigned short*)((char*)d_ws + xbytes);
    int n8 = M * K / 8;
    cast_x_kernel<<<dim3((n8 + 255) / 256), dim3(256), 0, stream>>>(x, xb, n8);
    int t8 = N * K / 8;
    make_weff_kernel<<<dim3((t8 + 255) / 256), dim3(256), 0, stream>>>(W, A, Bm, wb, scale, K, R, t8);
    if (fast256) {
      int grid = (M / 256) * (N / 256);
      gemm256_bt_bias<<<dim3(grid), dim3(512), 0, stream>>>(xb, wb, bias, out, M, N, K);
    } else {
      int grid = (M / 128) * (N / 128);
      gemm_bt_bias<<<dim3(grid), dim3(256), 0, stream>>>(xb, wb, bias, out, M, N, K);
    }
  } else {
    float* h = (float*)d_ws;
    lora_h_kernel<<<dim3(M), dim3(64), 0, stream>>>(x, A, h, scale, K, R);
    int grid = (M / 64) * (N / 64);
    fgemm_fallback<<<dim3(grid), dim3(256), 0, stream>>>(x, W, Bm, bias, h, out, M, N, K, R);
  }
}

// Round 4
// 346.121 us; speedup vs baseline: 1.4031x; 1.0359x over previous
//
#include <hip/hip_runtime.h>
#include <hip/hip_bf16.h>

typedef short bf16x8 __attribute__((ext_vector_type(8)));
typedef float f32x4 __attribute__((ext_vector_type(4)));
typedef unsigned short ushort8v __attribute__((ext_vector_type(8)));

#define SBAR() asm volatile("s_barrier" ::: "memory")
#define LGKM0() do { asm volatile("s_waitcnt lgkmcnt(0)" ::: "memory"); \
    __builtin_amdgcn_sched_barrier(0); } while (0)

__device__ __forceinline__ unsigned short f2bf(float f) {
  unsigned u = __builtin_bit_cast(unsigned, f);
  u += 0x7fffu + ((u >> 16) & 1u);   // round-to-nearest-even
  return (unsigned short)(u >> 16);
}

__device__ __forceinline__ void gload_lds16(const unsigned short* g, unsigned short* l) {
  __builtin_amdgcn_global_load_lds((const __attribute__((address_space(1))) void*)g,
                                   (__attribute__((address_space(3))) void*)l, 16, 0, 0);
}

// ---------------- fused prep: xb = bf16(x); wb = bf16(W + scale*B@A) ----------------
__global__ __launch_bounds__(256) void prep_kernel(const float* __restrict__ x,
                                                   const float* __restrict__ W,
                                                   const float* __restrict__ A,
                                                   const float* __restrict__ Bm,
                                                   unsigned short* __restrict__ xb,
                                                   unsigned short* __restrict__ wb,
                                                   float scale, int K, int R, int n8, int t8) {
  int i = blockIdx.x * 256 + threadIdx.x;
  if (i < n8) {
    const float4* p = (const float4*)x + (size_t)i * 2;
    float4 a = p[0], b = p[1];
    ushort8v v;
    v[0] = f2bf(a.x); v[1] = f2bf(a.y); v[2] = f2bf(a.z); v[3] = f2bf(a.w);
    v[4] = f2bf(b.x); v[5] = f2bf(b.y); v[6] = f2bf(b.z); v[7] = f2bf(b.w);
    *((ushort8v*)xb + i) = v;
    return;
  }
  int idx = i - n8;
  if (idx >= t8) return;
  int perRow = K >> 3;
  int n = idx / perRow;
  int d0 = (idx - n * perRow) << 3;
  const float4* wp = (const float4*)(W + (size_t)n * K + d0);
  float4 w0 = wp[0], w1 = wp[1];
  float acc[8] = {w0.x, w0.y, w0.z, w0.w, w1.x, w1.y, w1.z, w1.w};
#pragma unroll 4
  for (int r = 0; r < R; ++r) {
    float c = Bm[(size_t)n * R + r] * scale;
    const float4* ap = (const float4*)(A + (size_t)r * K + d0);
    float4 a0 = ap[0], a1 = ap[1];
    acc[0] += c * a0.x; acc[1] += c * a0.y; acc[2] += c * a0.z; acc[3] += c * a0.w;
    acc[4] += c * a1.x; acc[5] += c * a1.y; acc[6] += c * a1.z; acc[7] += c * a1.w;
  }
  ushort8v v;
#pragma unroll
  for (int j = 0; j < 8; ++j) v[j] = f2bf(acc[j]);
  *((ushort8v*)wb + idx) = v;
}

// ---------------- 256x256 2-phase/K-tile deep-pipeline bf16 GEMM ----------------
// BK=32, 8 waves (2x4) each owning 128x64, 4 LDS buffers staged 3 K-tiles ahead.
// Per K-tile: 2 phases x {ds_read frags | issue 2 gload_lds | SBAR | lgkmcnt(0) |
// setprio 16 MFMA | SBAR}; counted vmcnt(8/4/0) at end-of-tile only.
// Buffer layout (bytes): A rows 0..255 at [0,16384); B rows 0..255 at [16384,32768).
__global__ __launch_bounds__(512, 2) void gemm256_bt_bias(const unsigned short* __restrict__ Xb,
                                                          const unsigned short* __restrict__ Wb,
                                                          const float* __restrict__ bias,
                                                          float* __restrict__ C,
                                                          int M, int N, int K) {
  __shared__ __align__(16) unsigned short lds[4][16384];
  const int t = threadIdx.x;
  const int wave = t >> 6, lane = t & 63;
  const int fr = lane & 15, kc = lane >> 4;
  const int wr = wave >> 2, wc = wave & 3;

  const int NTn = N >> 8;
  const int nwg = gridDim.x;
  int bid = blockIdx.x;
  if ((nwg & 7) == 0) bid = (bid & 7) * (nwg >> 3) + (bid >> 3);  // XCD swizzle
  const int tm = bid / NTn, tn = bid % NTn;
  const int m0 = tm << 8, n0 = tn << 8;

  // staging: LDS[row][lc] = G[row][lc ^ ((row>>1)&3)]; lane t: row=t>>2, lc=t&3.
  const int srow = t >> 2;
  const int gch  = (t & 3) ^ ((t >> 3) & 3);
  const unsigned short* gA0 = Xb + (size_t)(m0 + srow) * K + gch * 8;
  const unsigned short* gA1 = gA0 + (size_t)128 * K;
  const unsigned short* gB0 = Wb + (size_t)(n0 + srow) * K + gch * 8;
  const unsigned short* gB1 = gB0 + (size_t)128 * K;
  const int stA0 = wave * 512;
  const int stA1 = 4096 + wave * 512;
  const int stB0 = 8192 + wave * 512;
  const int stB1 = 12288 + wave * 512;

  // per-lane read byte-offsets (tile-independent), 2-way-max bank aliasing
  int offA[8], offB[4];
#pragma unroll
  for (int m = 0; m < 8; ++m) {
    int row = wr * 128 + m * 16 + fr;
    offA[m] = row * 64 + (((kc ^ (row >> 1)) & 3) << 4);
  }
#pragma unroll
  for (int n = 0; n < 4; ++n) {
    int row = wc * 64 + n * 16 + fr;
    offB[n] = 16384 + row * 64 + (((kc ^ (row >> 1)) & 3) << 4);
  }

  f32x4 acc[8][4];
#pragma unroll
  for (int m = 0; m < 8; ++m)
#pragma unroll
    for (int n = 0; n < 4; ++n) acc[m][n] = (f32x4){0.f, 0.f, 0.f, 0.f};

  const int NT = K >> 5;

#define STAGE_A(tt) do {                                 \
    unsigned short* sb_ = &lds[(tt) & 3][0];             \
    const int ko_ = (tt) * 32;                           \
    gload_lds16(gA0 + ko_, sb_ + stA0);                  \
    gload_lds16(gA1 + ko_, sb_ + stA1);                  \
  } while (0)
#define STAGE_B(tt) do {                                 \
    unsigned short* sb_ = &lds[(tt) & 3][0];             \
    const int ko_ = (tt) * 32;                           \
    gload_lds16(gB0 + ko_, sb_ + stB0);                  \
    gload_lds16(gB1 + ko_, sb_ + stB1);                  \
  } while (0)

  // VM: literal string for end-of-tile counted vmcnt.
  // Steady state: need tile tt+1 landed; newer outstanding = (tt+2):4 + (tt+3):4 = 8.
#define TILE(tt, DOSTAGE, VM) do {                                                \
    const char* p_ = (const char*)&lds[(tt) & 3][0];                              \
    bf16x8 av_[4], bv_[4];                                                        \
    _Pragma("unroll") for (int n = 0; n < 4; ++n)                                 \
      bv_[n] = *(const bf16x8*)(p_ + offB[n]);                                    \
    _Pragma("unroll") for (int m = 0; m < 4; ++m)                                 \
      av_[m] = *(const bf16x8*)(p_ + offA[m]);                                    \
    if (DOSTAGE) { STAGE_A((tt) + 3); }                                           \
    SBAR();                                                                       \
    LGKM0();                                                                      \
    __builtin_amdgcn_s_setprio(1);                                                \
    _Pragma("unroll") for (int m = 0; m < 4; ++m)                                 \
      _Pragma("unroll") for (int n = 0; n < 4; ++n)                               \
        acc[m][n] = __builtin_amdgcn_mfma_f32_16x16x32_bf16(av_[m], bv_[n], acc[m][n], 0, 0, 0); \
    __builtin_amdgcn_s_setprio(0);                                                \
    SBAR();                                                                       \
    _Pragma("unroll") for (int m = 0; m < 4; ++m)                                 \
      av_[m] = *(const bf16x8*)(p_ + offA[4 + m]);                                \
    if (DOSTAGE) { STAGE_B((tt) + 3); }                                           \
    asm volatile("s_waitcnt vmcnt(" VM ")" ::: "memory");                         \
    SBAR();                                                                       \
    LGKM0();                                                                      \
    __builtin_amdgcn_s_setprio(1);                                                \
    _Pragma("unroll") for (int m = 0; m < 4; ++m)                                 \
      _Pragma("unroll") for (int n = 0; n < 4; ++n)                               \
        acc[4 + m][n] = __builtin_amdgcn_mfma_f32_16x16x32_bf16(av_[m], bv_[n], acc[4 + m][n], 0, 0, 0); \
    __builtin_amdgcn_s_setprio(0);                                                \
    SBAR();                                                                       \
  } while (0)

  // prologue: stage tiles 0,1,2 (12 loads); wait tile 0 (8 newer outstanding)
  STAGE_A(0); STAGE_B(0); STAGE_A(1); STAGE_B(1); STAGE_A(2); STAGE_B(2);
  asm volatile("s_waitcnt vmcnt(8)" ::: "memory");
  SBAR();

  for (int tt = 0; tt < NT - 3; ++tt) TILE(tt, 1, "8");
  TILE(NT - 3, 0, "4");
  TILE(NT - 2, 0, "0");
  TILE(NT - 1, 0, "0");

  // epilogue: D map col = lane&15, row = (lane>>4)*4 + reg
  const int crow = (lane >> 4) * 4;
  const int ccol = lane & 15;
#pragma unroll
  for (int n = 0; n < 4; ++n) {
    int col = n0 + wc * 64 + n * 16 + ccol;
    float bv = bias[col];
#pragma unroll
    for (int m = 0; m < 8; ++m) {
      int row = m0 + wr * 128 + m * 16 + crow;
      float* cp = C + (size_t)row * N + col;
#pragma unroll
      for (int r = 0; r < 4; ++r) cp[(size_t)r * N] = acc[m][n][r] + bv;
    }
  }
#undef STAGE_A
#undef STAGE_B
#undef TILE
}

// ---------------- 128x128 m97-structure fallback GEMM ----------------
__global__ __launch_bounds__(256) void gemm_bt_bias(const unsigned short* __restrict__ Xb,
                                                    const unsigned short* __restrict__ Wb,
                                                    const float* __restrict__ bias,
                                                    float* __restrict__ C,
                                                    int M, int N, int K) {
  __shared__ unsigned short sA[128 * 32];
  __shared__ unsigned short sB[128 * 32];
  const int t = threadIdx.x;
  const int wave = t >> 6, lane = t & 63;
  const int NT = N >> 7;
  const int nwg = gridDim.x;
  int bid = blockIdx.x;
  if ((nwg & 7) == 0) bid = (bid & 7) * (nwg >> 3) + (bid >> 3);
  const int tm = bid / NT, tn = bid % NT;
  const int m0 = tm << 7, n0 = tn << 7;
  const int wr = wave >> 1, wc = wave & 1;

  f32x4 acc[4][4];
#pragma unroll
  for (int m = 0; m < 4; ++m)
#pragma unroll
    for (int n = 0; n < 4; ++n) acc[m][n] = (f32x4){0.f, 0.f, 0.f, 0.f};

  const unsigned short* gA0 = Xb + (size_t)(m0 + (t >> 2)) * K + (t & 3) * 8;
  const unsigned short* gA1 = Xb + (size_t)(m0 + 64 + (t >> 2)) * K + (t & 3) * 8;
  const unsigned short* gB0 = Wb + (size_t)(n0 + (t >> 2)) * K + (t & 3) * 8;
  const unsigned short* gB1 = Wb + (size_t)(n0 + 64 + (t >> 2)) * K + (t & 3) * 8;
  unsigned short* lA0 = sA + (size_t)(wave * 64) * 8;
  unsigned short* lA1 = sA + (size_t)(256 + wave * 64) * 8;
  unsigned short* lB0 = sB + (size_t)(wave * 64) * 8;
  unsigned short* lB1 = sB + (size_t)(256 + wave * 64) * 8;

  const int rrow = lane & 15;
  const int rk = (lane >> 4) * 8;

  for (int k0 = 0; k0 < K; k0 += 32) {
    gload_lds16(gA0 + k0, lA0);
    gload_lds16(gA1 + k0, lA1);
    gload_lds16(gB0 + k0, lB0);
    gload_lds16(gB1 + k0, lB1);
    __syncthreads();
    bf16x8 af[4], bfr[4];
#pragma unroll
    for (int m = 0; m < 4; ++m)
      af[m] = *(const bf16x8*)&sA[(size_t)(wr * 64 + m * 16 + rrow) * 32 + rk];
#pragma unroll
    for (int n = 0; n < 4; ++n)
      bfr[n] = *(const bf16x8*)&sB[(size_t)(wc * 64 + n * 16 + rrow) * 32 + rk];
#pragma unroll
    for (int m = 0; m < 4; ++m)
#pragma unroll
      for (int n = 0; n < 4; ++n)
        acc[m][n] = __builtin_amdgcn_mfma_f32_16x16x32_bf16(af[m], bfr[n], acc[m][n], 0, 0, 0);
    __syncthreads();
  }
  const int crow0 = (lane >> 4) * 4;
  const int ccol = lane & 15;
#pragma unroll
  for (int n = 0; n < 4; ++n) {
    int col = n0 + wc * 64 + n * 16 + ccol;
    float bv = bias[col];
#pragma unroll
    for (int m = 0; m < 4; ++m) {
      int row = m0 + wr * 64 + m * 16 + crow0;
      float* cp = C + (size_t)row * N + col;
#pragma unroll
      for (int r = 0; r < 4; ++r) cp[(size_t)r * N] = acc[m][n][r] + bv;
    }
  }
}

// ---------------- fp32 fallback ----------------
__global__ __launch_bounds__(64) void lora_h_kernel(const float* __restrict__ x,
                                                    const float* __restrict__ A,
                                                    float* __restrict__ h,
                                                    float scale, int K, int R) {
  int m = blockIdx.x, lane = threadIdx.x;
  float acc[16];
#pragma unroll
  for (int r = 0; r < 16; ++r) acc[r] = 0.f;
  for (int d = lane; d < K; d += 64) {
    float xv = x[(size_t)m * K + d];
    for (int r = 0; r < R; ++r) acc[r] += xv * A[(size_t)r * K + d];
  }
  for (int off = 32; off; off >>= 1)
    for (int r = 0; r < R; ++r) acc[r] += __shfl_down(acc[r], off);
  if (lane == 0)
    for (int r = 0; r < R; ++r) h[(size_t)m * R + r] = acc[r] * scale;
}

__global__ __launch_bounds__(256) void fgemm_fallback(const float* __restrict__ X,
                                                      const float* __restrict__ W,
                                                      const float* __restrict__ Bm,
                                                      const float* __restrict__ bias,
                                                      const float* __restrict__ h,
                                                      float* __restrict__ C,
                                                      int M, int N, int K, int R) {
  __shared__ float sX[64][20];
  __shared__ float sW[64][20];
  int nt = N >> 6;
  int bx = blockIdx.x % nt, by = blockIdx.x / nt;
  int m0 = by << 6, n0 = bx << 6;
  int t = threadIdx.x;
  int tx = t & 15, ty = t >> 4;
  float acc[4][4] = {};
  int lr = t >> 2, lc = (t & 3) << 2;
  for (int k0 = 0; k0 < K; k0 += 16) {
    *(float4*)&sX[lr][lc] = *(const float4*)&X[(size_t)(m0 + lr) * K + k0 + lc];
    *(float4*)&sW[lr][lc] = *(const float4*)&W[(size_t)(n0 + lr) * K + k0 + lc];
    __syncthreads();
#pragma unroll
    for (int kk = 0; kk < 16; ++kk) {
      float a[4], b[4];
#pragma unroll
      for (int i = 0; i < 4; ++i) a[i] = sX[ty * 4 + i][kk];
#pragma unroll
      for (int j = 0; j < 4; ++j) b[j] = sW[tx * 4 + j][kk];
#pragma unroll
      for (int i = 0; i < 4; ++i)
#pragma unroll
        for (int j = 0; j < 4; ++j) acc[i][j] += a[i] * b[j];
    }
    __syncthreads();
  }
#pragma unroll
  for (int i = 0; i < 4; ++i) {
    int row = m0 + ty * 4 + i;
#pragma unroll
    for (int j = 0; j < 4; ++j) {
      int col = n0 + tx * 4 + j;
      float lo = 0.f;
      for (int r = 0; r < R; ++r) lo += h[(size_t)row * R + r] * Bm[(size_t)col * R + r];
      C[(size_t)row * N + col] = acc[i][j] + bias[col] + lo;
    }
  }
}

extern "C" void kernel_launch(void* const* d_in, const int* in_sizes, int n_in,
                              void* d_out, int out_size, void* d_ws, size_t ws_size,
                              hipStream_t stream) {
  const float* x    = (const float*)d_in[0];
  const float* W    = (const float*)d_in[1];
  const float* A    = (const float*)d_in[2];
  const float* Bm   = (const float*)d_in[3];
  const float* bias = (const float*)d_in[4];
  float* out = (float*)d_out;

  const int N = in_sizes[4];
  const int R = in_sizes[3] / N;
  const int K = in_sizes[2] / R;
  const int M = in_sizes[0] / K;
  const float scale = 16.0f / (float)R;

  const size_t xbytes = (size_t)M * K * 2;
  const size_t wbytes = (size_t)N * K * 2;
  const bool ws_ok = (ws_size >= xbytes + wbytes);
  const bool fast256 = ws_ok && (M % 256 == 0) && (N % 256 == 0) && (K % 32 == 0) && (K >= 128);
  const bool fast128 = ws_ok && (M % 128 == 0) && (N % 128 == 0) && (K % 32 == 0);

  if (fast256 || fast128) {
    unsigned short* xb = (unsigned short*)d_ws;
    unsigned short* wb = (unsigned short*)((char*)d_ws + xbytes);
    int n8 = M * K / 8;
    int t8 = N * K / 8;
    int total = n8 + t8;
    prep_kernel<<<dim3((total + 255) / 256), dim3(256), 0, stream>>>(x, W, A, Bm, xb, wb,
                                                                     scale, K, R, n8, t8);
    if (fast256) {
      int grid = (M / 256) * (N / 256);
      gemm256_bt_bias<<<dim3(grid), dim3(512), 0, stream>>>(xb, wb, bias, out, M, N, K);
    } else {
      int grid = (M / 128) * (N / 128);
      gemm_bt_bias<<<dim3(grid), dim3(256), 0, stream>>>(xb, wb, bias, out, M, N, K);
    }
  } else {
    float* h = (float*)d_ws;
    lora_h_kernel<<<dim3(M), dim3(64), 0, stream>>>(x, A, h, scale, K, R);
    int grid = (M / 64) * (N / 64);
    fgemm_fallback<<<dim3(grid), dim3(256), 0, stream>>>(x, W, Bm, bias, h, out, M, N, K, R);
  }
}

// Round 5
// 340.920 us; speedup vs baseline: 1.4245x; 1.0153x over previous
//
#include <hip/hip_runtime.h>
#include <hip/hip_bf16.h>

typedef short bf16x8 __attribute__((ext_vector_type(8)));
typedef float f32x4 __attribute__((ext_vector_type(4)));
typedef unsigned short ushort8v __attribute__((ext_vector_type(8)));

#define SBAR() asm volatile("s_barrier" ::: "memory")

__device__ __forceinline__ unsigned short f2bf(float f) {
  unsigned u = __builtin_bit_cast(unsigned, f);
  u += 0x7fffu + ((u >> 16) & 1u);   // round-to-nearest-even
  return (unsigned short)(u >> 16);
}

__device__ __forceinline__ void gload_lds16(const unsigned short* g, unsigned short* l) {
  __builtin_amdgcn_global_load_lds((const __attribute__((address_space(1))) void*)g,
                                   (__attribute__((address_space(3))) void*)l, 16, 0, 0);
}

// ---------------- fused prep: xb = bf16(x); wb = bf16(W + scale*B@A) ----------------
__global__ __launch_bounds__(256) void prep_kernel(const float* __restrict__ x,
                                                   const float* __restrict__ W,
                                                   const float* __restrict__ A,
                                                   const float* __restrict__ Bm,
                                                   unsigned short* __restrict__ xb,
                                                   unsigned short* __restrict__ wb,
                                                   float scale, int K, int R, int n8, int t8) {
  int i = blockIdx.x * 256 + threadIdx.x;
  if (i < n8) {
    const float4* p = (const float4*)x + (size_t)i * 2;
    float4 a = p[0], b = p[1];
    ushort8v v;
    v[0] = f2bf(a.x); v[1] = f2bf(a.y); v[2] = f2bf(a.z); v[3] = f2bf(a.w);
    v[4] = f2bf(b.x); v[5] = f2bf(b.y); v[6] = f2bf(b.z); v[7] = f2bf(b.w);
    *((ushort8v*)xb + i) = v;
    return;
  }
  int idx = i - n8;
  if (idx >= t8) return;
  int perRow = K >> 3;
  int n = idx / perRow;
  int d0 = (idx - n * perRow) << 3;
  const float4* wp = (const float4*)(W + (size_t)n * K + d0);
  float4 w0 = wp[0], w1 = wp[1];
  float acc[8] = {w0.x, w0.y, w0.z, w0.w, w1.x, w1.y, w1.z, w1.w};
#pragma unroll 4
  for (int r = 0; r < R; ++r) {
    float c = Bm[(size_t)n * R + r] * scale;
    const float4* ap = (const float4*)(A + (size_t)r * K + d0);
    float4 a0 = ap[0], a1 = ap[1];
    acc[0] += c * a0.x; acc[1] += c * a0.y; acc[2] += c * a0.z; acc[3] += c * a0.w;
    acc[4] += c * a1.x; acc[5] += c * a1.y; acc[6] += c * a1.z; acc[7] += c * a1.w;
  }
  ushort8v v;
#pragma unroll
  for (int j = 0; j < 8; ++j) v[j] = f2bf(acc[j]);
  *((ushort8v*)wb + idx) = v;
}

// ---------------- 256x256 pipelined bf16 GEMM: C = Xb @ Wb^T + bias ----------------
// BK=32, 8 waves (2x4) each owning 128x64. 4 LDS buffers staged 3 tiles ahead
// (vmcnt 8/4/0). Register-level software pipeline: frag ds_reads issue inside the
// PREVIOUS MFMA window, waited with counted lgkmcnt(4/8) -> LDS pipe runs under
// the MFMA clusters (LDS-BW roofline ~62% MfmaUtil for this tile shape).
// Buffer layout (bytes): A rows 0..255 at [0,16384); B rows 0..255 at [16384,32768).
__global__ __launch_bounds__(512, 2) void gemm256_bt_bias(const unsigned short* __restrict__ Xb,
                                                          const unsigned short* __restrict__ Wb,
                                                          const float* __restrict__ bias,
                                                          float* __restrict__ C,
                                                          int M, int N, int K) {
  __shared__ __align__(16) unsigned short lds[4][16384];
  const int t = threadIdx.x;
  const int wave = t >> 6, lane = t & 63;
  const int fr = lane & 15, kc = lane >> 4;
  const int wr = wave >> 2, wc = wave & 3;

  const int NTn = N >> 8;
  const int nwg = gridDim.x;
  int bid = blockIdx.x;
  if ((nwg & 7) == 0) bid = (bid & 7) * (nwg >> 3) + (bid >> 3);  // XCD swizzle
  const int tm = bid / NTn, tn = bid % NTn;
  const int m0 = tm << 8, n0 = tn << 8;

  // staging: LDS[row][lc] = G[row][lc ^ ((row>>1)&3)]; lane t: row=t>>2, lc=t&3.
  const int srow = t >> 2;
  const int gch  = (t & 3) ^ ((t >> 3) & 3);
  const unsigned short* gA0 = Xb + (size_t)(m0 + srow) * K + gch * 8;
  const unsigned short* gA1 = gA0 + (size_t)128 * K;
  const unsigned short* gB0 = Wb + (size_t)(n0 + srow) * K + gch * 8;
  const unsigned short* gB1 = gB0 + (size_t)128 * K;
  const int stA0 = wave * 512;
  const int stA1 = 4096 + wave * 512;
  const int stB0 = 8192 + wave * 512;
  const int stB1 = 12288 + wave * 512;

  // per-lane read byte-offsets (tile-independent), 2-way-max bank aliasing
  int offA[8], offB[4];
#pragma unroll
  for (int m = 0; m < 8; ++m) {
    int row = wr * 128 + m * 16 + fr;
    offA[m] = row * 64 + (((kc ^ (row >> 1)) & 3) << 4);
  }
#pragma unroll
  for (int n = 0; n < 4; ++n) {
    int row = wc * 64 + n * 16 + fr;
    offB[n] = 16384 + row * 64 + (((kc ^ (row >> 1)) & 3) << 4);
  }

  f32x4 acc[8][4];
#pragma unroll
  for (int m = 0; m < 8; ++m)
#pragma unroll
    for (int n = 0; n < 4; ++n) acc[m][n] = (f32x4){0.f, 0.f, 0.f, 0.f};

  const int NT = K >> 5;   // even (K % 64 == 0 enforced by launcher)

  bf16x8 bv0[4], avA0[4], bv1[4], avA1[4], avB[4];

#define STAGE_A(tt) do {                                 \
    unsigned short* sb_ = &lds[(tt) & 3][0];             \
    const int ko_ = (tt) * 32;                           \
    gload_lds16(gA0 + ko_, sb_ + stA0);                  \
    gload_lds16(gA1 + ko_, sb_ + stA1);                  \
  } while (0)
#define STAGE_B(tt) do {                                 \
    unsigned short* sb_ = &lds[(tt) & 3][0];             \
    const int ko_ = (tt) * 32;                           \
    gload_lds16(gB0 + ko_, sb_ + stB0);                  \
    gload_lds16(gB1 + ko_, sb_ + stB1);                  \
  } while (0)
#define READ_BV_AVA(tt, BV, AVA) do {                                             \
    const char* p_ = (const char*)&lds[(tt) & 3][0];                              \
    _Pragma("unroll") for (int n = 0; n < 4; ++n)                                 \
      BV[n] = *(const bf16x8*)(p_ + offB[n]);                                     \
    _Pragma("unroll") for (int m = 0; m < 4; ++m)                                 \
      AVA[m] = *(const bf16x8*)(p_ + offA[m]);                                    \
  } while (0)

  // TILE(tt): Q0 uses BVc/AVAc (read during previous Q1 window);
  // avB(tt) issued pre-Q0, waited at Q1 with lgkmcnt(8) while next tile's
  // BVn/AVAn (issued after the vmcnt+SBAR that certifies buffer tt+1) fly.
#define TILE(tt, BVc, AVAc, BVn, AVAn, DOSTAGE, VM, DONEXT) do {                  \
    { const char* p_ = (const char*)&lds[(tt) & 3][0];                            \
      _Pragma("unroll") for (int m = 0; m < 4; ++m)                               \
        avB[m] = *(const bf16x8*)(p_ + offA[4 + m]); }                            \
    if (DOSTAGE) { STAGE_A((tt) + 3); }                                           \
    SBAR();                                                                       \
    asm volatile("s_waitcnt lgkmcnt(4)" ::: "memory");  /* BVc,AVAc landed */     \
    __builtin_amdgcn_sched_barrier(0);                                            \
    __builtin_amdgcn_s_setprio(1);                                                \
    _Pragma("unroll") for (int m = 0; m < 4; ++m)                                 \
      _Pragma("unroll") for (int n = 0; n < 4; ++n)                               \
        acc[m][n] = __builtin_amdgcn_mfma_f32_16x16x32_bf16(AVAc[m], BVc[n], acc[m][n], 0, 0, 0); \
    __builtin_amdgcn_s_setprio(0);                                                \
    SBAR();                                                                       \
    if (DOSTAGE) { STAGE_B((tt) + 3); }                                           \
    asm volatile("s_waitcnt vmcnt(" VM ")" ::: "memory"); /* tile tt+1 landed */  \
    SBAR();                                            /* b(tt+1) valid for all */\
    if (DONEXT) { READ_BV_AVA((tt) + 1, BVn, AVAn);                               \
      asm volatile("s_waitcnt lgkmcnt(8)" ::: "memory");  /* avB landed */        \
    } else {                                                                      \
      asm volatile("s_waitcnt lgkmcnt(0)" ::: "memory");                          \
    }                                                                             \
    __builtin_amdgcn_sched_barrier(0);                                            \
    __builtin_amdgcn_s_setprio(1);                                                \
    _Pragma("unroll") for (int m = 0; m < 4; ++m)                                 \
      _Pragma("unroll") for (int n = 0; n < 4; ++n)                               \
        acc[4 + m][n] = __builtin_amdgcn_mfma_f32_16x16x32_bf16(avB[m], BVc[n], acc[4 + m][n], 0, 0, 0); \
    __builtin_amdgcn_s_setprio(0);                                                \
    SBAR();                                                                       \
  } while (0)

  // prologue: stage tiles 0,1,2; certify tile 0; preload its bv/avA
  STAGE_A(0); STAGE_B(0); STAGE_A(1); STAGE_B(1); STAGE_A(2); STAGE_B(2);
  asm volatile("s_waitcnt vmcnt(8)" ::: "memory");
  SBAR();
  READ_BV_AVA(0, bv0, avA0);

  int tt = 0;
  for (; tt + 5 < NT; tt += 2) {
    TILE(tt,     bv0, avA0, bv1, avA1, 1, "8", 1);
    TILE(tt + 1, bv1, avA1, bv0, avA0, 1, "8", 1);
  }
  // tt == NT-4 here (NT even)
  TILE(NT - 4, bv0, avA0, bv1, avA1, 1, "8", 1);
  TILE(NT - 3, bv1, avA1, bv0, avA0, 0, "4", 1);
  TILE(NT - 2, bv0, avA0, bv1, avA1, 0, "0", 1);
  TILE(NT - 1, bv1, avA1, bv0, avA0, 0, "0", 0);

  // epilogue: D map col = lane&15, row = (lane>>4)*4 + reg
  const int crow = (lane >> 4) * 4;
  const int ccol = lane & 15;
#pragma unroll
  for (int n = 0; n < 4; ++n) {
    int col = n0 + wc * 64 + n * 16 + ccol;
    float bv = bias[col];
#pragma unroll
    for (int m = 0; m < 8; ++m) {
      int row = m0 + wr * 128 + m * 16 + crow;
      float* cp = C + (size_t)row * N + col;
#pragma unroll
      for (int r = 0; r < 4; ++r) cp[(size_t)r * N] = acc[m][n][r] + bv;
    }
  }
#undef STAGE_A
#undef STAGE_B
#undef READ_BV_AVA
#undef TILE
}

// ---------------- 128x128 m97-structure fallback GEMM ----------------
__global__ __launch_bounds__(256) void gemm_bt_bias(const unsigned short* __restrict__ Xb,
                                                    const unsigned short* __restrict__ Wb,
                                                    const float* __restrict__ bias,
                                                    float* __restrict__ C,
                                                    int M, int N, int K) {
  __shared__ unsigned short sA[128 * 32];
  __shared__ unsigned short sB[128 * 32];
  const int t = threadIdx.x;
  const int wave = t >> 6, lane = t & 63;
  const int NT = N >> 7;
  const int nwg = gridDim.x;
  int bid = blockIdx.x;
  if ((nwg & 7) == 0) bid = (bid & 7) * (nwg >> 3) + (bid >> 3);
  const int tm = bid / NT, tn = bid % NT;
  const int m0 = tm << 7, n0 = tn << 7;
  const int wr = wave >> 1, wc = wave & 1;

  f32x4 acc[4][4];
#pragma unroll
  for (int m = 0; m < 4; ++m)
#pragma unroll
    for (int n = 0; n < 4; ++n) acc[m][n] = (f32x4){0.f, 0.f, 0.f, 0.f};

  const unsigned short* gA0 = Xb + (size_t)(m0 + (t >> 2)) * K + (t & 3) * 8;
  const unsigned short* gA1 = Xb + (size_t)(m0 + 64 + (t >> 2)) * K + (t & 3) * 8;
  const unsigned short* gB0 = Wb + (size_t)(n0 + (t >> 2)) * K + (t & 3) * 8;
  const unsigned short* gB1 = Wb + (size_t)(n0 + 64 + (t >> 2)) * K + (t & 3) * 8;
  unsigned short* lA0 = sA + (size_t)(wave * 64) * 8;
  unsigned short* lA1 = sA + (size_t)(256 + wave * 64) * 8;
  unsigned short* lB0 = sB + (size_t)(wave * 64) * 8;
  unsigned short* lB1 = sB + (size_t)(256 + wave * 64) * 8;

  const int rrow = lane & 15;
  const int rk = (lane >> 4) * 8;

  for (int k0 = 0; k0 < K; k0 += 32) {
    gload_lds16(gA0 + k0, lA0);
    gload_lds16(gA1 + k0, lA1);
    gload_lds16(gB0 + k0, lB0);
    gload_lds16(gB1 + k0, lB1);
    __syncthreads();
    bf16x8 af[4], bfr[4];
#pragma unroll
    for (int m = 0; m < 4; ++m)
      af[m] = *(const bf16x8*)&sA[(size_t)(wr * 64 + m * 16 + rrow) * 32 + rk];
#pragma unroll
    for (int n = 0; n < 4; ++n)
      bfr[n] = *(const bf16x8*)&sB[(size_t)(wc * 64 + n * 16 + rrow) * 32 + rk];
#pragma unroll
    for (int m = 0; m < 4; ++m)
#pragma unroll
      for (int n = 0; n < 4; ++n)
        acc[m][n] = __builtin_amdgcn_mfma_f32_16x16x32_bf16(af[m], bfr[n], acc[m][n], 0, 0, 0);
    __syncthreads();
  }
  const int crow0 = (lane >> 4) * 4;
  const int ccol = lane & 15;
#pragma unroll
  for (int n = 0; n < 4; ++n) {
    int col = n0 + wc * 64 + n * 16 + ccol;
    float bv = bias[col];
#pragma unroll
    for (int m = 0; m < 4; ++m) {
      int row = m0 + wr * 64 + m * 16 + crow0;
      float* cp = C + (size_t)row * N + col;
#pragma unroll
      for (int r = 0; r < 4; ++r) cp[(size_t)r * N] = acc[m][n][r] + bv;
    }
  }
}

// ---------------- fp32 fallback ----------------
__global__ __launch_bounds__(64) void lora_h_kernel(const float* __restrict__ x,
                                                    const float* __restrict__ A,
                                                    float* __restrict__ h,
                                                    float scale, int K, int R) {
  int m = blockIdx.x, lane = threadIdx.x;
  float acc[16];
#pragma unroll
  for (int r = 0; r < 16; ++r) acc[r] = 0.f;
  for (int d = lane; d < K; d += 64) {
    float xv = x[(size_t)m * K + d];
    for (int r = 0; r < R; ++r) acc[r] += xv * A[(size_t)r * K + d];
  }
  for (int off = 32; off; off >>= 1)
    for (int r = 0; r < R; ++r) acc[r] += __shfl_down(acc[r], off);
  if (lane == 0)
    for (int r = 0; r < R; ++r) h[(size_t)m * R + r] = acc[r] * scale;
}

__global__ __launch_bounds__(256) void fgemm_fallback(const float* __restrict__ X,
                                                      const float* __restrict__ W,
                                                      const float* __restrict__ Bm,
                                                      const float* __restrict__ bias,
                                                      const float* __restrict__ h,
                                                      float* __restrict__ C,
                                                      int M, int N, int K, int R) {
  __shared__ float sX[64][20];
  __shared__ float sW[64][20];
  int nt = N >> 6;
  int bx = blockIdx.x % nt, by = blockIdx.x / nt;
  int m0 = by << 6, n0 = bx << 6;
  int t = threadIdx.x;
  int tx = t & 15, ty = t >> 4;
  float acc[4][4] = {};
  int lr = t >> 2, lc = (t & 3) << 2;
  for (int k0 = 0; k0 < K; k0 += 16) {
    *(float4*)&sX[lr][lc] = *(const float4*)&X[(size_t)(m0 + lr) * K + k0 + lc];
    *(float4*)&sW[lr][lc] = *(const float4*)&W[(size_t)(n0 + lr) * K + k0 + lc];
    __syncthreads();
#pragma unroll
    for (int kk = 0; kk < 16; ++kk) {
      float a[4], b[4];
#pragma unroll
      for (int i = 0; i < 4; ++i) a[i] = sX[ty * 4 + i][kk];
#pragma unroll
      for (int j = 0; j < 4; ++j) b[j] = sW[tx * 4 + j][kk];
#pragma unroll
      for (int i = 0; i < 4; ++i)
#pragma unroll
        for (int j = 0; j < 4; ++j) acc[i][j] += a[i] * b[j];
    }
    __syncthreads();
  }
#pragma unroll
  for (int i = 0; i < 4; ++i) {
    int row = m0 + ty * 4 + i;
#pragma unroll
    for (int j = 0; j < 4; ++j) {
      int col = n0 + tx * 4 + j;
      float lo = 0.f;
      for (int r = 0; r < R; ++r) lo += h[(size_t)row * R + r] * Bm[(size_t)col * R + r];
      C[(size_t)row * N + col] = acc[i][j] + bias[col] + lo;
    }
  }
}

extern "C" void kernel_launch(void* const* d_in, const int* in_sizes, int n_in,
                              void* d_out, int out_size, void* d_ws, size_t ws_size,
                              hipStream_t stream) {
  const float* x    = (const float*)d_in[0];
  const float* W    = (const float*)d_in[1];
  const float* A    = (const float*)d_in[2];
  const float* Bm   = (const float*)d_in[3];
  const float* bias = (const float*)d_in[4];
  float* out = (float*)d_out;

  const int N = in_sizes[4];
  const int R = in_sizes[3] / N;
  const int K = in_sizes[2] / R;
  const int M = in_sizes[0] / K;
  const float scale = 16.0f / (float)R;

  const size_t xbytes = (size_t)M * K * 2;
  const size_t wbytes = (size_t)N * K * 2;
  const bool ws_ok = (ws_size >= xbytes + wbytes);
  const bool fast256 = ws_ok && (M % 256 == 0) && (N % 256 == 0) && (K % 64 == 0) && (K >= 128);
  const bool fast128 = ws_ok && (M % 128 == 0) && (N % 128 == 0) && (K % 32 == 0);

  if (fast256 || fast128) {
    unsigned short* xb = (unsigned short*)d_ws;
    unsigned short* wb = (unsigned short*)((char*)d_ws + xbytes);
    int n8 = M * K / 8;
    int t8 = N * K / 8;
    int total = n8 + t8;
    prep_kernel<<<dim3((total + 255) / 256), dim3(256), 0, stream>>>(x, W, A, Bm, xb, wb,
                                                                     scale, K, R, n8, t8);
    if (fast256) {
      int grid = (M / 256) * (N / 256);
      gemm256_bt_bias<<<dim3(grid), dim3(512), 0, stream>>>(xb, wb, bias, out, M, N, K);
    } else {
      int grid = (M / 128) * (N / 128);
      gemm_bt_bias<<<dim3(grid), dim3(256), 0, stream>>>(xb, wb, bias, out, M, N, K);
    }
  } else {
    float* h = (float*)d_ws;
    lora_h_kernel<<<dim3(M), dim3(64), 0, stream>>>(x, A, h, scale, K, R);
    int grid = (M / 64) * (N / 64);
    fgemm_fallback<<<dim3(grid), dim3(256), 0, stream>>>(x, W, Bm, bias, h, out, M, N, K, R);
  }
}

// Round 6
// 339.106 us; speedup vs baseline: 1.4321x; 1.0054x over previous
//
#include <hip/hip_runtime.h>
#include <hip/hip_bf16.h>

typedef short bf16x8 __attribute__((ext_vector_type(8)));
typedef float f32x4 __attribute__((ext_vector_type(4)));
typedef unsigned short ushort8v __attribute__((ext_vector_type(8)));

#define SBAR() asm volatile("s_barrier" ::: "memory")

__device__ __forceinline__ unsigned short f2bf(float f) {
  unsigned u = __builtin_bit_cast(unsigned, f);
  u += 0x7fffu + ((u >> 16) & 1u);   // round-to-nearest-even
  return (unsigned short)(u >> 16);
}

__device__ __forceinline__ void gload_lds16(const unsigned short* g, unsigned short* l) {
  __builtin_amdgcn_global_load_lds((const __attribute__((address_space(1))) void*)g,
                                   (__attribute__((address_space(3))) void*)l, 16, 0, 0);
}

// ---------------- fused prep: xb = bf16(x); wb = bf16(W + scale*B@A) ----------------
__global__ __launch_bounds__(256) void prep_kernel(const float* __restrict__ x,
                                                   const float* __restrict__ W,
                                                   const float* __restrict__ A,
                                                   const float* __restrict__ Bm,
                                                   unsigned short* __restrict__ xb,
                                                   unsigned short* __restrict__ wb,
                                                   float scale, int K, int R, int n8, int t8) {
  int i = blockIdx.x * 256 + threadIdx.x;
  if (i < n8) {
    const float4* p = (const float4*)x + (size_t)i * 2;
    float4 a = p[0], b = p[1];
    ushort8v v;
    v[0] = f2bf(a.x); v[1] = f2bf(a.y); v[2] = f2bf(a.z); v[3] = f2bf(a.w);
    v[4] = f2bf(b.x); v[5] = f2bf(b.y); v[6] = f2bf(b.z); v[7] = f2bf(b.w);
    *((ushort8v*)xb + i) = v;
    return;
  }
  int idx = i - n8;
  if (idx >= t8) return;
  int perRow = K >> 3;
  int n = idx / perRow;
  int d0 = (idx - n * perRow) << 3;
  const float4* wp = (const float4*)(W + (size_t)n * K + d0);
  float4 w0 = wp[0], w1 = wp[1];
  float acc[8] = {w0.x, w0.y, w0.z, w0.w, w1.x, w1.y, w1.z, w1.w};
#pragma unroll 4
  for (int r = 0; r < R; ++r) {
    float c = Bm[(size_t)n * R + r] * scale;
    const float4* ap = (const float4*)(A + (size_t)r * K + d0);
    float4 a0 = ap[0], a1 = ap[1];
    acc[0] += c * a0.x; acc[1] += c * a0.y; acc[2] += c * a0.z; acc[3] += c * a0.w;
    acc[4] += c * a1.x; acc[5] += c * a1.y; acc[6] += c * a1.z; acc[7] += c * a1.w;
  }
  ushort8v v;
#pragma unroll
  for (int j = 0; j < 8; ++j) v[j] = f2bf(acc[j]);
  *((ushort8v*)wb + idx) = v;
}

// ---------------- 256x256 pipelined bf16 GEMM: C = Xb @ Wb^T + bias ----------------
// BK=32, 8 waves (2x4) each owning 128x64. 4 LDS buffers staged 3 tiles ahead
// (vmcnt 8/4/0). TWO barriers per K-tile only:
//   certify-SBAR (after vmcnt: buf tt+1 visible to all waves)
//   end-SBAR     (after all waves' lgkm drain of avB: buf tt safe to overwrite)
// Q0 entry is barrier-free (own-wave counted lgkmcnt) -> waves slip phase,
// LDS pipe drains under other waves' MFMA windows.
// Buffer layout (bytes): A rows 0..255 at [0,16384); B rows 0..255 at [16384,32768).
__global__ __launch_bounds__(512, 2) void gemm256_bt_bias(const unsigned short* __restrict__ Xb,
                                                          const unsigned short* __restrict__ Wb,
                                                          const float* __restrict__ bias,
                                                          float* __restrict__ C,
                                                          int M, int N, int K) {
  __shared__ __align__(16) unsigned short lds[4][16384];
  const int t = threadIdx.x;
  const int wave = t >> 6, lane = t & 63;
  const int fr = lane & 15, kc = lane >> 4;
  const int wr = wave >> 2, wc = wave & 3;

  const int NTn = N >> 8;
  const int nwg = gridDim.x;
  int bid = blockIdx.x;
  if ((nwg & 7) == 0) bid = (bid & 7) * (nwg >> 3) + (bid >> 3);  // XCD swizzle
  const int tm = bid / NTn, tn = bid % NTn;
  const int m0 = tm << 8, n0 = tn << 8;

  // staging: LDS[row][lc] = G[row][lc ^ ((row>>1)&3)]; lane t: row=t>>2, lc=t&3.
  const int srow = t >> 2;
  const int gch  = (t & 3) ^ ((t >> 3) & 3);
  const unsigned short* gA0 = Xb + (size_t)(m0 + srow) * K + gch * 8;
  const unsigned short* gA1 = gA0 + (size_t)128 * K;
  const unsigned short* gB0 = Wb + (size_t)(n0 + srow) * K + gch * 8;
  const unsigned short* gB1 = gB0 + (size_t)128 * K;
  const int stA0 = wave * 512;
  const int stA1 = 4096 + wave * 512;
  const int stB0 = 8192 + wave * 512;
  const int stB1 = 12288 + wave * 512;

  // per-lane read byte-offsets (tile-independent), 2-way-max bank aliasing
  int offA[8], offB[4];
#pragma unroll
  for (int m = 0; m < 8; ++m) {
    int row = wr * 128 + m * 16 + fr;
    offA[m] = row * 64 + (((kc ^ (row >> 1)) & 3) << 4);
  }
#pragma unroll
  for (int n = 0; n < 4; ++n) {
    int row = wc * 64 + n * 16 + fr;
    offB[n] = 16384 + row * 64 + (((kc ^ (row >> 1)) & 3) << 4);
  }

  f32x4 acc[8][4];
#pragma unroll
  for (int m = 0; m < 8; ++m)
#pragma unroll
    for (int n = 0; n < 4; ++n) acc[m][n] = (f32x4){0.f, 0.f, 0.f, 0.f};

  const int NT = K >> 5;   // even (K % 64 == 0 enforced by launcher)

  bf16x8 bv0[4], avA0[4], bv1[4], avA1[4], avB[4];

#define STAGE_A(tt) do {                                 \
    unsigned short* sb_ = &lds[(tt) & 3][0];             \
    const int ko_ = (tt) * 32;                           \
    gload_lds16(gA0 + ko_, sb_ + stA0);                  \
    gload_lds16(gA1 + ko_, sb_ + stA1);                  \
  } while (0)
#define STAGE_B(tt) do {                                 \
    unsigned short* sb_ = &lds[(tt) & 3][0];             \
    const int ko_ = (tt) * 32;                           \
    gload_lds16(gB0 + ko_, sb_ + stB0);                  \
    gload_lds16(gB1 + ko_, sb_ + stB1);                  \
  } while (0)
#define READ_BV_AVA(tt, BV, AVA) do {                                             \
    const char* p_ = (const char*)&lds[(tt) & 3][0];                              \
    _Pragma("unroll") for (int n = 0; n < 4; ++n)                                 \
      BV[n] = *(const bf16x8*)(p_ + offB[n]);                                     \
    _Pragma("unroll") for (int m = 0; m < 4; ++m)                                 \
      AVA[m] = *(const bf16x8*)(p_ + offA[m]);                                    \
  } while (0)

  // TILE(tt): Q0 gated only by own-wave lgkmcnt(4) (bv/avA read last tile);
  // avB(tt) issued pre-Q0, drained at lgkm(8) pre-Q1; certify-SBAR after
  // vmcnt makes buf tt+1 visible; end-SBAR makes buf tt overwritable.
#define TILE(tt, BVc, AVAc, BVn, AVAn, DOSTAGE, VM, DONEXT) do {                  \
    { const char* p_ = (const char*)&lds[(tt) & 3][0];                            \
      _Pragma("unroll") for (int m = 0; m < 4; ++m)                               \
        avB[m] = *(const bf16x8*)(p_ + offA[4 + m]); }                            \
    if (DOSTAGE) { STAGE_A((tt) + 3); }                                           \
    asm volatile("s_waitcnt lgkmcnt(4)" ::: "memory");  /* BVc,AVAc landed */     \
    __builtin_amdgcn_sched_barrier(0);                                            \
    __builtin_amdgcn_s_setprio(1);                                                \
    _Pragma("unroll") for (int m = 0; m < 4; ++m)                                 \
      _Pragma("unroll") for (int n = 0; n < 4; ++n)                               \
        acc[m][n] = __builtin_amdgcn_mfma_f32_16x16x32_bf16(AVAc[m], BVc[n], acc[m][n], 0, 0, 0); \
    __builtin_amdgcn_s_setprio(0);                                                \
    if (DOSTAGE) { STAGE_B((tt) + 3); }                                           \
    asm volatile("s_waitcnt vmcnt(" VM ")" ::: "memory"); /* tile tt+1 landed */  \
    SBAR();                                          /* certify buf tt+1 */       \
    if (DONEXT) { READ_BV_AVA((tt) + 1, BVn, AVAn);                               \
      asm volatile("s_waitcnt lgkmcnt(8)" ::: "memory");  /* avB landed */        \
    } else {                                                                      \
      asm volatile("s_waitcnt lgkmcnt(0)" ::: "memory");                          \
    }                                                                             \
    __builtin_amdgcn_sched_barrier(0);                                            \
    __builtin_amdgcn_s_setprio(1);                                                \
    _Pragma("unroll") for (int m = 0; m < 4; ++m)                                 \
      _Pragma("unroll") for (int n = 0; n < 4; ++n)                               \
        acc[4 + m][n] = __builtin_amdgcn_mfma_f32_16x16x32_bf16(avB[m], BVc[n], acc[4 + m][n], 0, 0, 0); \
    __builtin_amdgcn_s_setprio(0);                                                \
    SBAR();                                          /* buf tt overwritable */    \
  } while (0)

  // prologue: stage tiles 0,1,2; certify tile 0; preload its bv/avA
  STAGE_A(0); STAGE_B(0); STAGE_A(1); STAGE_B(1); STAGE_A(2); STAGE_B(2);
  asm volatile("s_waitcnt vmcnt(8)" ::: "memory");
  SBAR();
  READ_BV_AVA(0, bv0, avA0);

  int tt = 0;
  for (; tt + 5 < NT; tt += 2) {
    TILE(tt,     bv0, avA0, bv1, avA1, 1, "8", 1);
    TILE(tt + 1, bv1, avA1, bv0, avA0, 1, "8", 1);
  }
  // tt == NT-4 here (NT even)
  TILE(NT - 4, bv0, avA0, bv1, avA1, 1, "8", 1);
  TILE(NT - 3, bv1, avA1, bv0, avA0, 0, "4", 1);
  TILE(NT - 2, bv0, avA0, bv1, avA1, 0, "0", 1);
  TILE(NT - 1, bv1, avA1, bv0, avA0, 0, "0", 0);

  // epilogue: D map col = lane&15, row = (lane>>4)*4 + reg
  const int crow = (lane >> 4) * 4;
  const int ccol = lane & 15;
#pragma unroll
  for (int n = 0; n < 4; ++n) {
    int col = n0 + wc * 64 + n * 16 + ccol;
    float bv = bias[col];
#pragma unroll
    for (int m = 0; m < 8; ++m) {
      int row = m0 + wr * 128 + m * 16 + crow;
      float* cp = C + (size_t)row * N + col;
#pragma unroll
      for (int r = 0; r < 4; ++r) cp[(size_t)r * N] = acc[m][n][r] + bv;
    }
  }
#undef STAGE_A
#undef STAGE_B
#undef READ_BV_AVA
#undef TILE
}

// ---------------- 128x128 m97-structure fallback GEMM ----------------
__global__ __launch_bounds__(256) void gemm_bt_bias(const unsigned short* __restrict__ Xb,
                                                    const unsigned short* __restrict__ Wb,
                                                    const float* __restrict__ bias,
                                                    float* __restrict__ C,
                                                    int M, int N, int K) {
  __shared__ unsigned short sA[128 * 32];
  __shared__ unsigned short sB[128 * 32];
  const int t = threadIdx.x;
  const int wave = t >> 6, lane = t & 63;
  const int NT = N >> 7;
  const int nwg = gridDim.x;
  int bid = blockIdx.x;
  if ((nwg & 7) == 0) bid = (bid & 7) * (nwg >> 3) + (bid >> 3);
  const int tm = bid / NT, tn = bid % NT;
  const int m0 = tm << 7, n0 = tn << 7;
  const int wr = wave >> 1, wc = wave & 1;

  f32x4 acc[4][4];
#pragma unroll
  for (int m = 0; m < 4; ++m)
#pragma unroll
    for (int n = 0; n < 4; ++n) acc[m][n] = (f32x4){0.f, 0.f, 0.f, 0.f};

  const unsigned short* gA0 = Xb + (size_t)(m0 + (t >> 2)) * K + (t & 3) * 8;
  const unsigned short* gA1 = Xb + (size_t)(m0 + 64 + (t >> 2)) * K + (t & 3) * 8;
  const unsigned short* gB0 = Wb + (size_t)(n0 + (t >> 2)) * K + (t & 3) * 8;
  const unsigned short* gB1 = Wb + (size_t)(n0 + 64 + (t >> 2)) * K + (t & 3) * 8;
  unsigned short* lA0 = sA + (size_t)(wave * 64) * 8;
  unsigned short* lA1 = sA + (size_t)(256 + wave * 64) * 8;
  unsigned short* lB0 = sB + (size_t)(wave * 64) * 8;
  unsigned short* lB1 = sB + (size_t)(256 + wave * 64) * 8;

  const int rrow = lane & 15;
  const int rk = (lane >> 4) * 8;

  for (int k0 = 0; k0 < K; k0 += 32) {
    gload_lds16(gA0 + k0, lA0);
    gload_lds16(gA1 + k0, lA1);
    gload_lds16(gB0 + k0, lB0);
    gload_lds16(gB1 + k0, lB1);
    __syncthreads();
    bf16x8 af[4], bfr[4];
#pragma unroll
    for (int m = 0; m < 4; ++m)
      af[m] = *(const bf16x8*)&sA[(size_t)(wr * 64 + m * 16 + rrow) * 32 + rk];
#pragma unroll
    for (int n = 0; n < 4; ++n)
      bfr[n] = *(const bf16x8*)&sB[(size_t)(wc * 64 + n * 16 + rrow) * 32 + rk];
#pragma unroll
    for (int m = 0; m < 4; ++m)
#pragma unroll
      for (int n = 0; n < 4; ++n)
        acc[m][n] = __builtin_amdgcn_mfma_f32_16x16x32_bf16(af[m], bfr[n], acc[m][n], 0, 0, 0);
    __syncthreads();
  }
  const int crow0 = (lane >> 4) * 4;
  const int ccol = lane & 15;
#pragma unroll
  for (int n = 0; n < 4; ++n) {
    int col = n0 + wc * 64 + n * 16 + ccol;
    float bv = bias[col];
#pragma unroll
    for (int m = 0; m < 4; ++m) {
      int row = m0 + wr * 64 + m * 16 + crow0;
      float* cp = C + (size_t)row * N + col;
#pragma unroll
      for (int r = 0; r < 4; ++r) cp[(size_t)r * N] = acc[m][n][r] + bv;
    }
  }
}

// ---------------- fp32 fallback ----------------
__global__ __launch_bounds__(64) void lora_h_kernel(const float* __restrict__ x,
                                                    const float* __restrict__ A,
                                                    float* __restrict__ h,
                                                    float scale, int K, int R) {
  int m = blockIdx.x, lane = threadIdx.x;
  float acc[16];
#pragma unroll
  for (int r = 0; r < 16; ++r) acc[r] = 0.f;
  for (int d = lane; d < K; d += 64) {
    float xv = x[(size_t)m * K + d];
    for (int r = 0; r < R; ++r) acc[r] += xv * A[(size_t)r * K + d];
  }
  for (int off = 32; off; off >>= 1)
    for (int r = 0; r < R; ++r) acc[r] += __shfl_down(acc[r], off);
  if (lane == 0)
    for (int r = 0; r < R; ++r) h[(size_t)m * R + r] = acc[r] * scale;
}

__global__ __launch_bounds__(256) void fgemm_fallback(const float* __restrict__ X,
                                                      const float* __restrict__ W,
                                                      const float* __restrict__ Bm,
                                                      const float* __restrict__ bias,
                                                      const float* __restrict__ h,
                                                      float* __restrict__ C,
                                                      int M, int N, int K, int R) {
  __shared__ float sX[64][20];
  __shared__ float sW[64][20];
  int nt = N >> 6;
  int bx = blockIdx.x % nt, by = blockIdx.x / nt;
  int m0 = by << 6, n0 = bx << 6;
  int t = threadIdx.x;
  int tx = t & 15, ty = t >> 4;
  float acc[4][4] = {};
  int lr = t >> 2, lc = (t & 3) << 2;
  for (int k0 = 0; k0 < K; k0 += 16) {
    *(float4*)&sX[lr][lc] = *(const float4*)&X[(size_t)(m0 + lr) * K + k0 + lc];
    *(float4*)&sW[lr][lc] = *(const float4*)&W[(size_t)(n0 + lr) * K + k0 + lc];
    __syncthreads();
#pragma unroll
    for (int kk = 0; kk < 16; ++kk) {
      float a[4], b[4];
#pragma unroll
      for (int i = 0; i < 4; ++i) a[i] = sX[ty * 4 + i][kk];
#pragma unroll
      for (int j = 0; j < 4; ++j) b[j] = sW[tx * 4 + j][kk];
#pragma unroll
      for (int i = 0; i < 4; ++i)
#pragma unroll
        for (int j = 0; j < 4; ++j) acc[i][j] += a[i] * b[j];
    }
    __syncthreads();
  }
#pragma unroll
  for (int i = 0; i < 4; ++i) {
    int row = m0 + ty * 4 + i;
#pragma unroll
    for (int j = 0; j < 4; ++j) {
      int col = n0 + tx * 4 + j;
      float lo = 0.f;
      for (int r = 0; r < R; ++r) lo += h[(size_t)row * R + r] * Bm[(size_t)col * R + r];
      C[(size_t)row * N + col] = acc[i][j] + bias[col] + lo;
    }
  }
}

extern "C" void kernel_launch(void* const* d_in, const int* in_sizes, int n_in,
                              void* d_out, int out_size, void* d_ws, size_t ws_size,
                              hipStream_t stream) {
  const float* x    = (const float*)d_in[0];
  const float* W    = (const float*)d_in[1];
  const float* A    = (const float*)d_in[2];
  const float* Bm   = (const float*)d_in[3];
  const float* bias = (const float*)d_in[4];
  float* out = (float*)d_out;

  const int N = in_sizes[4];
  const int R = in_sizes[3] / N;
  const int K = in_sizes[2] / R;
  const int M = in_sizes[0] / K;
  const float scale = 16.0f / (float)R;

  const size_t xbytes = (size_t)M * K * 2;
  const size_t wbytes = (size_t)N * K * 2;
  const bool ws_ok = (ws_size >= xbytes + wbytes);
  const bool fast256 = ws_ok && (M % 256 == 0) && (N % 256 == 0) && (K % 64 == 0) && (K >= 128);
  const bool fast128 = ws_ok && (M % 128 == 0) && (N % 128 == 0) && (K % 32 == 0);

  if (fast256 || fast128) {
    unsigned short* xb = (unsigned short*)d_ws;
    unsigned short* wb = (unsigned short*)((char*)d_ws + xbytes);
    int n8 = M * K / 8;
    int t8 = N * K / 8;
    int total = n8 + t8;
    prep_kernel<<<dim3((total + 255) / 256), dim3(256), 0, stream>>>(x, W, A, Bm, xb, wb,
                                                                     scale, K, R, n8, t8);
    if (fast256) {
      int grid = (M / 256) * (N / 256);
      gemm256_bt_bias<<<dim3(grid), dim3(512), 0, stream>>>(xb, wb, bias, out, M, N, K);
    } else {
      int grid = (M / 128) * (N / 128);
      gemm_bt_bias<<<dim3(grid), dim3(256), 0, stream>>>(xb, wb, bias, out, M, N, K);
    }
  } else {
    float* h = (float*)d_ws;
    lora_h_kernel<<<dim3(M), dim3(64), 0, stream>>>(x, A, h, scale, K, R);
    int grid = (M / 64) * (N / 64);
    fgemm_fallback<<<dim3(grid), dim3(256), 0, stream>>>(x, W, Bm, bias, h, out, M, N, K, R);
  }
}

// Round 7
// 338.724 us; speedup vs baseline: 1.4337x; 1.0011x over previous
//
#include <hip/hip_runtime.h>
#include <hip/hip_bf16.h>

typedef short bf16x8 __attribute__((ext_vector_type(8)));
typedef float f32x4 __attribute__((ext_vector_type(4)));
typedef unsigned short ushort8v __attribute__((ext_vector_type(8)));

#define SBAR() asm volatile("s_barrier" ::: "memory")

__device__ __forceinline__ unsigned short f2bf(float f) {
  unsigned u = __builtin_bit_cast(unsigned, f);
  u += 0x7fffu + ((u >> 16) & 1u);   // round-to-nearest-even
  return (unsigned short)(u >> 16);
}

__device__ __forceinline__ void gload_lds16(const unsigned short* g, unsigned short* l) {
  __builtin_amdgcn_global_load_lds((const __attribute__((address_space(1))) void*)g,
                                   (__attribute__((address_space(3))) void*)l, 16, 0, 0);
}

// ---------------- fused prep: xb = bf16(x); wb = bf16(W + scale*B@A) ----------------
__global__ __launch_bounds__(256) void prep_kernel(const float* __restrict__ x,
                                                   const float* __restrict__ W,
                                                   const float* __restrict__ A,
                                                   const float* __restrict__ Bm,
                                                   unsigned short* __restrict__ xb,
                                                   unsigned short* __restrict__ wb,
                                                   float scale, int K, int R, int n8, int t8) {
  int i = blockIdx.x * 256 + threadIdx.x;
  if (i < n8) {
    const float4* p = (const float4*)x + (size_t)i * 2;
    float4 a = p[0], b = p[1];
    ushort8v v;
    v[0] = f2bf(a.x); v[1] = f2bf(a.y); v[2] = f2bf(a.z); v[3] = f2bf(a.w);
    v[4] = f2bf(b.x); v[5] = f2bf(b.y); v[6] = f2bf(b.z); v[7] = f2bf(b.w);
    *((ushort8v*)xb + i) = v;
    return;
  }
  int idx = i - n8;
  if (idx >= t8) return;
  int perRow = K >> 3;
  int n = idx / perRow;
  int d0 = (idx - n * perRow) << 3;
  const float4* wp = (const float4*)(W + (size_t)n * K + d0);
  float4 w0 = wp[0], w1 = wp[1];
  float acc[8] = {w0.x, w0.y, w0.z, w0.w, w1.x, w1.y, w1.z, w1.w};
#pragma unroll 4
  for (int r = 0; r < R; ++r) {
    float c = Bm[(size_t)n * R + r] * scale;
    const float4* ap = (const float4*)(A + (size_t)r * K + d0);
    float4 a0 = ap[0], a1 = ap[1];
    acc[0] += c * a0.x; acc[1] += c * a0.y; acc[2] += c * a0.z; acc[3] += c * a0.w;
    acc[4] += c * a1.x; acc[5] += c * a1.y; acc[6] += c * a1.z; acc[7] += c * a1.w;
  }
  ushort8v v;
#pragma unroll
  for (int j = 0; j < 8; ++j) v[j] = f2bf(acc[j]);
  *((ushort8v*)wb + idx) = v;
}

// ---------------- 256x256 pipelined bf16 GEMM: C = Xb @ Wb^T + bias ----------------
// BK=32, 8 waves (2x4) each owning 128x64. 4 LDS buffers staged 3 tiles ahead
// (vmcnt 8/4/0). FULL register double-buffer: all 12 frag reads of tile tt+1
// (bv4+avA4+avB4) issue right after tile tt's certify-SBAR -> >=1 tile lead,
// so counted lgkm waits never stall and the LDS pipe drains UNDER the MFMA
// windows (attacks the measured additive MFMA+LDS behavior).
// Buffer layout (bytes): A rows 0..255 at [0,16384); B rows 0..255 at [16384,32768).
__global__ __launch_bounds__(512, 2) void gemm256_bt_bias(const unsigned short* __restrict__ Xb,
                                                          const unsigned short* __restrict__ Wb,
                                                          const float* __restrict__ bias,
                                                          float* __restrict__ C,
                                                          int M, int N, int K) {
  __shared__ __align__(16) unsigned short lds[4][16384];
  const int t = threadIdx.x;
  const int wave = t >> 6, lane = t & 63;
  const int fr = lane & 15, kc = lane >> 4;
  const int wr = wave >> 2, wc = wave & 3;

  const int NTn = N >> 8;
  const int nwg = gridDim.x;
  int bid = blockIdx.x;
  if ((nwg & 7) == 0) bid = (bid & 7) * (nwg >> 3) + (bid >> 3);  // XCD swizzle
  const int tm = bid / NTn, tn = bid % NTn;
  const int m0 = tm << 8, n0 = tn << 8;

  // staging: LDS[row][lc] = G[row][lc ^ ((row>>1)&3)]; lane t: row=t>>2, lc=t&3.
  const int srow = t >> 2;
  const int gch  = (t & 3) ^ ((t >> 3) & 3);
  const unsigned short* gA0 = Xb + (size_t)(m0 + srow) * K + gch * 8;
  const unsigned short* gA1 = gA0 + (size_t)128 * K;
  const unsigned short* gB0 = Wb + (size_t)(n0 + srow) * K + gch * 8;
  const unsigned short* gB1 = gB0 + (size_t)128 * K;
  const int stA0 = wave * 512;
  const int stA1 = 4096 + wave * 512;
  const int stB0 = 8192 + wave * 512;
  const int stB1 = 12288 + wave * 512;

  // per-lane read byte-offsets (tile-independent), conflict-free (measured 0)
  int offA[8], offB[4];
#pragma unroll
  for (int m = 0; m < 8; ++m) {
    int row = wr * 128 + m * 16 + fr;
    offA[m] = row * 64 + (((kc ^ (row >> 1)) & 3) << 4);
  }
#pragma unroll
  for (int n = 0; n < 4; ++n) {
    int row = wc * 64 + n * 16 + fr;
    offB[n] = 16384 + row * 64 + (((kc ^ (row >> 1)) & 3) << 4);
  }

  f32x4 acc[8][4];
#pragma unroll
  for (int m = 0; m < 8; ++m)
#pragma unroll
    for (int n = 0; n < 4; ++n) acc[m][n] = (f32x4){0.f, 0.f, 0.f, 0.f};

  const int NT = K >> 5;   // even (K % 64 == 0 enforced by launcher)

  bf16x8 bv0[4], avA0[4], avB0[4], bv1[4], avA1[4], avB1[4];

#define STAGE_A(tt) do {                                 \
    unsigned short* sb_ = &lds[(tt) & 3][0];             \
    const int ko_ = (tt) * 32;                           \
    gload_lds16(gA0 + ko_, sb_ + stA0);                  \
    gload_lds16(gA1 + ko_, sb_ + stA1);                  \
  } while (0)
#define STAGE_B(tt) do {                                 \
    unsigned short* sb_ = &lds[(tt) & 3][0];             \
    const int ko_ = (tt) * 32;                           \
    gload_lds16(gB0 + ko_, sb_ + stB0);                  \
    gload_lds16(gB1 + ko_, sb_ + stB1);                  \
  } while (0)
  // issue order matters for counted lgkm: bv(4), avA(4), avB(4)
#define READ12(tt, BV, AVA, AVB) do {                                             \
    const char* p_ = (const char*)&lds[(tt) & 3][0];                              \
    _Pragma("unroll") for (int n = 0; n < 4; ++n)                                 \
      BV[n] = *(const bf16x8*)(p_ + offB[n]);                                     \
    _Pragma("unroll") for (int m = 0; m < 4; ++m)                                 \
      AVA[m] = *(const bf16x8*)(p_ + offA[m]);                                    \
    _Pragma("unroll") for (int m = 0; m < 4; ++m)                                 \
      AVB[m] = *(const bf16x8*)(p_ + offA[4 + m]);                                \
  } while (0)

  // TILE(tt): all operands of tile tt were read during tile tt-1 (>=1 tile lead).
  // lgkm(4): bv/avA done (own avB may fly). Q0 MFMA. stage tt+3. vmcnt: tile
  // tt+1 landed. certify-SBAR. READ12(tt+1) into other reg set. lgkm(12): own
  // avB done past the 12 new. Q1 MFMA. end-SBAR (buf tt free).
#define TILE(tt, BVc, AVAc, AVBc, BVn, AVAn, AVBn, DOSTAGE, VM, DONEXT) do {      \
    if (DOSTAGE) { STAGE_A((tt) + 3); }                                           \
    asm volatile("s_waitcnt lgkmcnt(4)" ::: "memory");                            \
    __builtin_amdgcn_sched_barrier(0);                                            \
    __builtin_amdgcn_s_setprio(1);                                                \
    _Pragma("unroll") for (int m = 0; m < 4; ++m)                                 \
      _Pragma("unroll") for (int n = 0; n < 4; ++n)                               \
        acc[m][n] = __builtin_amdgcn_mfma_f32_16x16x32_bf16(AVAc[m], BVc[n], acc[m][n], 0, 0, 0); \
    __builtin_amdgcn_s_setprio(0);                                                \
    if (DOSTAGE) { STAGE_B((tt) + 3); }                                           \
    asm volatile("s_waitcnt vmcnt(" VM ")" ::: "memory"); /* tile tt+1 landed */  \
    SBAR();                                          /* certify buf tt+1 */       \
    if (DONEXT) { READ12((tt) + 1, BVn, AVAn, AVBn);                              \
      asm volatile("s_waitcnt lgkmcnt(12)" ::: "memory");  /* own avB done */     \
    } else {                                                                      \
      asm volatile("s_waitcnt lgkmcnt(0)" ::: "memory");                          \
    }                                                                             \
    __builtin_amdgcn_sched_barrier(0);                                            \
    __builtin_amdgcn_s_setprio(1);                                                \
    _Pragma("unroll") for (int m = 0; m < 4; ++m)                                 \
      _Pragma("unroll") for (int n = 0; n < 4; ++n)                               \
        acc[4 + m][n] = __builtin_amdgcn_mfma_f32_16x16x32_bf16(AVBc[m], BVc[n], acc[4 + m][n], 0, 0, 0); \
    __builtin_amdgcn_s_setprio(0);                                                \
    SBAR();                                          /* buf tt overwritable */    \
  } while (0)

  // prologue: stage tiles 0,1,2; certify tile 0; preload ALL 12 frags of tile 0
  STAGE_A(0); STAGE_B(0); STAGE_A(1); STAGE_B(1); STAGE_A(2); STAGE_B(2);
  asm volatile("s_waitcnt vmcnt(8)" ::: "memory");
  SBAR();
  READ12(0, bv0, avA0, avB0);

  int tt = 0;
  for (; tt + 5 < NT; tt += 2) {
    TILE(tt,     bv0, avA0, avB0, bv1, avA1, avB1, 1, "8", 1);
    TILE(tt + 1, bv1, avA1, avB1, bv0, avA0, avB0, 1, "8", 1);
  }
  // tt == NT-4 here (NT even)
  TILE(NT - 4, bv0, avA0, avB0, bv1, avA1, avB1, 1, "8", 1);
  TILE(NT - 3, bv1, avA1, avB1, bv0, avA0, avB0, 0, "4", 1);
  TILE(NT - 2, bv0, avA0, avB0, bv1, avA1, avB1, 0, "0", 1);
  TILE(NT - 1, bv1, avA1, avB1, bv0, avA0, avB0, 0, "0", 0);

  // epilogue: D map col = lane&15, row = (lane>>4)*4 + reg
  const int crow = (lane >> 4) * 4;
  const int ccol = lane & 15;
#pragma unroll
  for (int n = 0; n < 4; ++n) {
    int col = n0 + wc * 64 + n * 16 + ccol;
    float bv = bias[col];
#pragma unroll
    for (int m = 0; m < 8; ++m) {
      int row = m0 + wr * 128 + m * 16 + crow;
      float* cp = C + (size_t)row * N + col;
#pragma unroll
      for (int r = 0; r < 4; ++r) cp[(size_t)r * N] = acc[m][n][r] + bv;
    }
  }
#undef STAGE_A
#undef STAGE_B
#undef READ12
#undef TILE
}

// ---------------- 128x128 m97-structure fallback GEMM ----------------
__global__ __launch_bounds__(256) void gemm_bt_bias(const unsigned short* __restrict__ Xb,
                                                    const unsigned short* __restrict__ Wb,
                                                    const float* __restrict__ bias,
                                                    float* __restrict__ C,
                                                    int M, int N, int K) {
  __shared__ unsigned short sA[128 * 32];
  __shared__ unsigned short sB[128 * 32];
  const int t = threadIdx.x;
  const int wave = t >> 6, lane = t & 63;
  const int NT = N >> 7;
  const int nwg = gridDim.x;
  int bid = blockIdx.x;
  if ((nwg & 7) == 0) bid = (bid & 7) * (nwg >> 3) + (bid >> 3);
  const int tm = bid / NT, tn = bid % NT;
  const int m0 = tm << 7, n0 = tn << 7;
  const int wr = wave >> 1, wc = wave & 1;

  f32x4 acc[4][4];
#pragma unroll
  for (int m = 0; m < 4; ++m)
#pragma unroll
    for (int n = 0; n < 4; ++n) acc[m][n] = (f32x4){0.f, 0.f, 0.f, 0.f};

  const unsigned short* gA0 = Xb + (size_t)(m0 + (t >> 2)) * K + (t & 3) * 8;
  const unsigned short* gA1 = Xb + (size_t)(m0 + 64 + (t >> 2)) * K + (t & 3) * 8;
  const unsigned short* gB0 = Wb + (size_t)(n0 + (t >> 2)) * K + (t & 3) * 8;
  const unsigned short* gB1 = Wb + (size_t)(n0 + 64 + (t >> 2)) * K + (t & 3) * 8;
  unsigned short* lA0 = sA + (size_t)(wave * 64) * 8;
  unsigned short* lA1 = sA + (size_t)(256 + wave * 64) * 8;
  unsigned short* lB0 = sB + (size_t)(wave * 64) * 8;
  unsigned short* lB1 = sB + (size_t)(256 + wave * 64) * 8;

  const int rrow = lane & 15;
  const int rk = (lane >> 4) * 8;

  for (int k0 = 0; k0 < K; k0 += 32) {
    gload_lds16(gA0 + k0, lA0);
    gload_lds16(gA1 + k0, lA1);
    gload_lds16(gB0 + k0, lB0);
    gload_lds16(gB1 + k0, lB1);
    __syncthreads();
    bf16x8 af[4], bfr[4];
#pragma unroll
    for (int m = 0; m < 4; ++m)
      af[m] = *(const bf16x8*)&sA[(size_t)(wr * 64 + m * 16 + rrow) * 32 + rk];
#pragma unroll
    for (int n = 0; n < 4; ++n)
      bfr[n] = *(const bf16x8*)&sB[(size_t)(wc * 64 + n * 16 + rrow) * 32 + rk];
#pragma unroll
    for (int m = 0; m < 4; ++m)
#pragma unroll
      for (int n = 0; n < 4; ++n)
        acc[m][n] = __builtin_amdgcn_mfma_f32_16x16x32_bf16(af[m], bfr[n], acc[m][n], 0, 0, 0);
    __syncthreads();
  }
  const int crow0 = (lane >> 4) * 4;
  const int ccol = lane & 15;
#pragma unroll
  for (int n = 0; n < 4; ++n) {
    int col = n0 + wc * 64 + n * 16 + ccol;
    float bv = bias[col];
#pragma unroll
    for (int m = 0; m < 4; ++m) {
      int row = m0 + wr * 64 + m * 16 + crow0;
      float* cp = C + (size_t)row * N + col;
#pragma unroll
      for (int r = 0; r < 4; ++r) cp[(size_t)r * N] = acc[m][n][r] + bv;
    }
  }
}

// ---------------- fp32 fallback ----------------
__global__ __launch_bounds__(64) void lora_h_kernel(const float* __restrict__ x,
                                                    const float* __restrict__ A,
                                                    float* __restrict__ h,
                                                    float scale, int K, int R) {
  int m = blockIdx.x, lane = threadIdx.x;
  float acc[16];
#pragma unroll
  for (int r = 0; r < 16; ++r) acc[r] = 0.f;
  for (int d = lane; d < K; d += 64) {
    float xv = x[(size_t)m * K + d];
    for (int r = 0; r < R; ++r) acc[r] += xv * A[(size_t)r * K + d];
  }
  for (int off = 32; off; off >>= 1)
    for (int r = 0; r < R; ++r) acc[r] += __shfl_down(acc[r], off);
  if (lane == 0)
    for (int r = 0; r < R; ++r) h[(size_t)m * R + r] = acc[r] * scale;
}

__global__ __launch_bounds__(256) void fgemm_fallback(const float* __restrict__ X,
                                                      const float* __restrict__ W,
                                                      const float* __restrict__ Bm,
                                                      const float* __restrict__ bias,
                                                      const float* __restrict__ h,
                                                      float* __restrict__ C,
                                                      int M, int N, int K, int R) {
  __shared__ float sX[64][20];
  __shared__ float sW[64][20];
  int nt = N >> 6;
  int bx = blockIdx.x % nt, by = blockIdx.x / nt;
  int m0 = by << 6, n0 = bx << 6;
  int t = threadIdx.x;
  int tx = t & 15, ty = t >> 4;
  float acc[4][4] = {};
  int lr = t >> 2, lc = (t & 3) << 2;
  for (int k0 = 0; k0 < K; k0 += 16) {
    *(float4*)&sX[lr][lc] = *(const float4*)&X[(size_t)(m0 + lr) * K + k0 + lc];
    *(float4*)&sW[lr][lc] = *(const float4*)&W[(size_t)(n0 + lr) * K + k0 + lc];
    __syncthreads();
#pragma unroll
    for (int kk = 0; kk < 16; ++kk) {
      float a[4], b[4];
#pragma unroll
      for (int i = 0; i < 4; ++i) a[i] = sX[ty * 4 + i][kk];
#pragma unroll
      for (int j = 0; j < 4; ++j) b[j] = sW[tx * 4 + j][kk];
#pragma unroll
      for (int i = 0; i < 4; ++i)
#pragma unroll
        for (int j = 0; j < 4; ++j) acc[i][j] += a[i] * b[j];
    }
    __syncthreads();
  }
#pragma unroll
  for (int i = 0; i < 4; ++i) {
    int row = m0 + ty * 4 + i;
#pragma unroll
    for (int j = 0; j < 4; ++j) {
      int col = n0 + tx * 4 + j;
      float lo = 0.f;
      for (int r = 0; r < R; ++r) lo += h[(size_t)row * R + r] * Bm[(size_t)col * R + r];
      C[(size_t)row * N + col] = acc[i][j] + bias[col] + lo;
    }
  }
}

extern "C" void kernel_launch(void* const* d_in, const int* in_sizes, int n_in,
                              void* d_out, int out_size, void* d_ws, size_t ws_size,
                              hipStream_t stream) {
  const float* x    = (const float*)d_in[0];
  const float* W    = (const float*)d_in[1];
  const float* A    = (const float*)d_in[2];
  const float* Bm   = (const float*)d_in[3];
  const float* bias = (const float*)d_in[4];
  float* out = (float*)d_out;

  const int N = in_sizes[4];
  const int R = in_sizes[3] / N;
  const int K = in_sizes[2] / R;
  const int M = in_sizes[0] / K;
  const float scale = 16.0f / (float)R;

  const size_t xbytes = (size_t)M * K * 2;
  const size_t wbytes = (size_t)N * K * 2;
  const bool ws_ok = (ws_size >= xbytes + wbytes);
  const bool fast256 = ws_ok && (M % 256 == 0) && (N % 256 == 0) && (K % 64 == 0) && (K >= 128);
  const bool fast128 = ws_ok && (M % 128 == 0) && (N % 128 == 0) && (K % 32 == 0);

  if (fast256 || fast128) {
    unsigned short* xb = (unsigned short*)d_ws;
    unsigned short* wb = (unsigned short*)((char*)d_ws + xbytes);
    int n8 = M * K / 8;
    int t8 = N * K / 8;
    int total = n8 + t8;
    prep_kernel<<<dim3((total + 255) / 256), dim3(256), 0, stream>>>(x, W, A, Bm, xb, wb,
                                                                     scale, K, R, n8, t8);
    if (fast256) {
      int grid = (M / 256) * (N / 256);
      gemm256_bt_bias<<<dim3(grid), dim3(512), 0, stream>>>(xb, wb, bias, out, M, N, K);
    } else {
      int grid = (M / 128) * (N / 128);
      gemm_bt_bias<<<dim3(grid), dim3(256), 0, stream>>>(xb, wb, bias, out, M, N, K);
    }
  } else {
    float* h = (float*)d_ws;
    lora_h_kernel<<<dim3(M), dim3(64), 0, stream>>>(x, A, h, scale, K, R);
    int grid = (M / 64) * (N / 64);
    fgemm_fallback<<<dim3(grid), dim3(256), 0, stream>>>(x, W, Bm, bias, h, out, M, N, K, R);
  }
}

// Round 8
// 330.740 us; speedup vs baseline: 1.4683x; 1.0241x over previous
//
#include <hip/hip_runtime.h>
#include <hip/hip_bf16.h>

typedef short bf16x8 __attribute__((ext_vector_type(8)));
typedef float f32x4 __attribute__((ext_vector_type(4)));
typedef unsigned short ushort8v __attribute__((ext_vector_type(8)));

#define SBAR() asm volatile("s_barrier" ::: "memory")
#define LGKM0() do { asm volatile("s_waitcnt lgkmcnt(0)" ::: "memory"); \
    __builtin_amdgcn_sched_barrier(0); } while (0)

__device__ __forceinline__ unsigned short f2bf(float f) {
  unsigned u = __builtin_bit_cast(unsigned, f);
  u += 0x7fffu + ((u >> 16) & 1u);   // round-to-nearest-even
  return (unsigned short)(u >> 16);
}

__device__ __forceinline__ void gload_lds16(const unsigned short* g, unsigned short* l) {
  __builtin_amdgcn_global_load_lds((const __attribute__((address_space(1))) void*)g,
                                   (__attribute__((address_space(3))) void*)l, 16, 0, 0);
}

// ---------------- fused prep: xb = bf16(x); wb = bf16(W + scale*B@A) ----------------
__global__ __launch_bounds__(256) void prep_kernel(const float* __restrict__ x,
                                                   const float* __restrict__ W,
                                                   const float* __restrict__ A,
                                                   const float* __restrict__ Bm,
                                                   unsigned short* __restrict__ xb,
                                                   unsigned short* __restrict__ wb,
                                                   float scale, int K, int R, int n8, int t8) {
  int i = blockIdx.x * 256 + threadIdx.x;
  if (i < n8) {
    const float4* p = (const float4*)x + (size_t)i * 2;
    float4 a = p[0], b = p[1];
    ushort8v v;
    v[0] = f2bf(a.x); v[1] = f2bf(a.y); v[2] = f2bf(a.z); v[3] = f2bf(a.w);
    v[4] = f2bf(b.x); v[5] = f2bf(b.y); v[6] = f2bf(b.z); v[7] = f2bf(b.w);
    *((ushort8v*)xb + i) = v;
    return;
  }
  int idx = i - n8;
  if (idx >= t8) return;
  int perRow = K >> 3;
  int n = idx / perRow;
  int d0 = (idx - n * perRow) << 3;
  const float4* wp = (const float4*)(W + (size_t)n * K + d0);
  float4 w0 = wp[0], w1 = wp[1];
  float acc[8] = {w0.x, w0.y, w0.z, w0.w, w1.x, w1.y, w1.z, w1.w};
#pragma unroll 4
  for (int r = 0; r < R; ++r) {
    float c = Bm[(size_t)n * R + r] * scale;
    const float4* ap = (const float4*)(A + (size_t)r * K + d0);
    float4 a0 = ap[0], a1 = ap[1];
    acc[0] += c * a0.x; acc[1] += c * a0.y; acc[2] += c * a0.z; acc[3] += c * a0.w;
    acc[4] += c * a1.x; acc[5] += c * a1.y; acc[6] += c * a1.z; acc[7] += c * a1.w;
  }
  ushort8v v;
#pragma unroll
  for (int j = 0; j < 8; ++j) v[j] = f2bf(acc[j]);
  *((ushort8v*)wb + idx) = v;
}

// ---------------- 256x256 8-phase bf16 GEMM (m201-template port) ----------------
// BK=64, 8 waves (2Mx4N, wave tile 128x64), 2 LDS buffers of 64KB.
// Per K-step c: 4 quadrant-phases, each {ds_read subtile | stage 2 sites |
// SBAR | lgkm(0) | setprio 16 MFMA | SBAR}. Stage ledger: A(c+1) at P1/P2
// (into buf[c+1] A-region, freed at c-1 P3-end); B(c+2) at P3/P4 (into buf[c]
// B-region, freed after this step's P2). One counted vmcnt per K-step at P4:
// need A(c+1) landed; newer outstanding = B(c+2) 4 loads -> vmcnt(4); tail 0.
// Buffer (bytes): A[256][64] at [0,32768); B[256][64] at [32768,65536).
// Swizzle: LDS chunk c16 holds global chunk c16 ^ (row&7) (16B chunks, 8/row).
__global__ __launch_bounds__(512, 2) void gemm256_bt_bias(const unsigned short* __restrict__ Xb,
                                                          const unsigned short* __restrict__ Wb,
                                                          const float* __restrict__ bias,
                                                          float* __restrict__ C,
                                                          int M, int N, int K) {
  __shared__ __align__(16) char lds[131072];
  const int t = threadIdx.x;
  const int wave = t >> 6, lane = t & 63;
  const int fr = lane & 15, kc = lane >> 4;
  const int wr = wave >> 2, wc = wave & 3;

  const int NTn = N >> 8;
  const int nwg = gridDim.x;
  int bid = blockIdx.x;
  if ((nwg & 7) == 0) bid = (bid & 7) * (nwg >> 3) + (bid >> 3);  // XCD swizzle
  const int tm = bid / NTn, tn = bid % NTn;
  const int m0 = tm << 8, n0 = tn << 8;

  // ---- staging: site s = 64 rows (8KB); thread t -> row s*64+(t>>3),
  // source chunk pre-swizzled; LDS dest linear (= t*16 within site). ----
  const int grow = t >> 3;
  const int gch8 = ((t & 7) ^ ((t >> 3) & 7)) << 3;
  const unsigned short* gA0 = Xb + (size_t)(m0 + grow) * K + gch8;
  const unsigned short* gB0 = Wb + (size_t)(n0 + grow) * K + gch8;
  char* stg = (char*)lds + wave * 1024;

  // ---- per-lane ds_read byte offsets (qm=0/qn=0 bases; ks variants) ----
  const int sw  = (lane & 7) << 4;
  const int cb0 = (kc << 4) ^ sw;            // ks=0 swizzled chunk byte
  const int cb1 = ((4 + kc) << 4) ^ sw;      // ks=1
  const int oA0 = (wr * 128 + fr) * 128 + cb0;
  const int oA1 = (wr * 128 + fr) * 128 + cb1;
  const int oB0 = 32768 + (wc * 64 + fr) * 128 + cb0;
  const int oB1 = 32768 + (wc * 64 + fr) * 128 + cb1;

  f32x4 acc[8][4];
#pragma unroll
  for (int m = 0; m < 8; ++m)
#pragma unroll
    for (int n = 0; n < 4; ++n) acc[m][n] = (f32x4){0.f, 0.f, 0.f, 0.f};

  bf16x8 aQa[8], aQb[8], bQ0[4], bQ1[4];   // [m*2+ks], [n*2+ks]
  const int NT = K >> 6;

#define STG_A(s, step) gload_lds16(gA0 + (size_t)(s) * 64 * K + (size_t)(step) * 64, \
    (unsigned short*)(stg + (((step) & 1) << 16) + (s) * 8192))
#define STG_B(s, step) gload_lds16(gB0 + (size_t)(s) * 64 * K + (size_t)(step) * 64, \
    (unsigned short*)(stg + (((step) & 1) << 16) + 32768 + (s) * 8192))

#define RD_A(dst, qmo, p_) do { \
    dst[0]=*(const bf16x8*)((p_)+oA0+(qmo));      dst[1]=*(const bf16x8*)((p_)+oA1+(qmo)); \
    dst[2]=*(const bf16x8*)((p_)+oA0+(qmo)+2048); dst[3]=*(const bf16x8*)((p_)+oA1+(qmo)+2048); \
    dst[4]=*(const bf16x8*)((p_)+oA0+(qmo)+4096); dst[5]=*(const bf16x8*)((p_)+oA1+(qmo)+4096); \
    dst[6]=*(const bf16x8*)((p_)+oA0+(qmo)+6144); dst[7]=*(const bf16x8*)((p_)+oA1+(qmo)+6144); } while (0)
#define RD_B(dst, qno, p_) do { \
    dst[0]=*(const bf16x8*)((p_)+oB0+(qno));      dst[1]=*(const bf16x8*)((p_)+oB1+(qno)); \
    dst[2]=*(const bf16x8*)((p_)+oB0+(qno)+2048); dst[3]=*(const bf16x8*)((p_)+oB1+(qno)+2048); } while (0)

#define MM(qm, qn, AR, BR) do { \
    __builtin_amdgcn_s_setprio(1); \
    _Pragma("unroll") for (int ks = 0; ks < 2; ++ks) \
    _Pragma("unroll") for (int m = 0; m < 4; ++m) \
    _Pragma("unroll") for (int n = 0; n < 2; ++n) \
      acc[(qm)*4+m][(qn)*2+n] = __builtin_amdgcn_mfma_f32_16x16x32_bf16( \
          AR[m*2+ks], BR[n*2+ks], acc[(qm)*4+m][(qn)*2+n], 0, 0, 0); \
    __builtin_amdgcn_s_setprio(0); } while (0)

#define KSTEP(c, STA, STB, VM) do { \
    const char* p_ = (const char*)lds + (((c) & 1) << 16); \
    /* P1: Q(0,0) */ \
    RD_A(aQa, 0, p_); RD_B(bQ0, 0, p_); \
    if (STA) { STG_A(0, (c) + 1); STG_A(1, (c) + 1); } \
    asm volatile("s_waitcnt lgkmcnt(8)" ::: "memory"); \
    SBAR(); LGKM0(); MM(0, 0, aQa, bQ0); SBAR(); \
    /* P2: Q(0,1) */ \
    RD_B(bQ1, 4096, p_); \
    if (STA) { STG_A(2, (c) + 1); STG_A(3, (c) + 1); } \
    SBAR(); LGKM0(); MM(0, 1, aQa, bQ1); SBAR(); \
    /* P3: Q(1,0) */ \
    RD_A(aQb, 8192, p_); \
    if (STB) { STG_B(0, (c) + 2); STG_B(1, (c) + 2); } \
    SBAR(); LGKM0(); MM(1, 0, aQb, bQ0); SBAR(); \
    /* P4: Q(1,1) + counted vmcnt (certify A(c+1) for next step) */ \
    if (STB) { STG_B(2, (c) + 2); STG_B(3, (c) + 2); } \
    asm volatile("s_waitcnt vmcnt(" VM ")" ::: "memory"); \
    SBAR(); MM(1, 1, aQb, bQ1); SBAR(); \
  } while (0)

  // prologue: A(0),B(0) -> buf0; B(1) -> buf1. Need A(0)+B(0) (first 8) landed:
  // newer = B(1) 4 -> vmcnt(4).
  STG_A(0, 0); STG_A(1, 0); STG_A(2, 0); STG_A(3, 0);
  STG_B(0, 0); STG_B(1, 0); STG_B(2, 0); STG_B(3, 0);
  STG_B(0, 1); STG_B(1, 1); STG_B(2, 1); STG_B(3, 1);
  asm volatile("s_waitcnt vmcnt(4)" ::: "memory");
  SBAR();

  int c = 0;
  for (; c < NT - 2; ++c) KSTEP(c, 1, 1, "4");
  KSTEP(NT - 2, 1, 0, "0");
  KSTEP(NT - 1, 0, 0, "0");

  // epilogue: D map col = lane&15, row = (lane>>4)*4 + reg
  const int crow = (lane >> 4) * 4;
  const int ccol = lane & 15;
#pragma unroll
  for (int n = 0; n < 4; ++n) {
    int col = n0 + wc * 64 + n * 16 + ccol;
    float bv = bias[col];
#pragma unroll
    for (int m = 0; m < 8; ++m) {
      int row = m0 + wr * 128 + m * 16 + crow;
      float* cp = C + (size_t)row * N + col;
#pragma unroll
      for (int r = 0; r < 4; ++r) cp[(size_t)r * N] = acc[m][n][r] + bv;
    }
  }
#undef STG_A
#undef STG_B
#undef RD_A
#undef RD_B
#undef MM
#undef KSTEP
}

// ---------------- 128x128 m97-structure fallback GEMM ----------------
__global__ __launch_bounds__(256) void gemm_bt_bias(const unsigned short* __restrict__ Xb,
                                                    const unsigned short* __restrict__ Wb,
                                                    const float* __restrict__ bias,
                                                    float* __restrict__ C,
                                                    int M, int N, int K) {
  __shared__ unsigned short sA[128 * 32];
  __shared__ unsigned short sB[128 * 32];
  const int t = threadIdx.x;
  const int wave = t >> 6, lane = t & 63;
  const int NT = N >> 7;
  const int nwg = gridDim.x;
  int bid = blockIdx.x;
  if ((nwg & 7) == 0) bid = (bid & 7) * (nwg >> 3) + (bid >> 3);
  const int tm = bid / NT, tn = bid % NT;
  const int m0 = tm << 7, n0 = tn << 7;
  const int wr = wave >> 1, wc = wave & 1;

  f32x4 acc[4][4];
#pragma unroll
  for (int m = 0; m < 4; ++m)
#pragma unroll
    for (int n = 0; n < 4; ++n) acc[m][n] = (f32x4){0.f, 0.f, 0.f, 0.f};

  const unsigned short* gA0 = Xb + (size_t)(m0 + (t >> 2)) * K + (t & 3) * 8;
  const unsigned short* gA1 = Xb + (size_t)(m0 + 64 + (t >> 2)) * K + (t & 3) * 8;
  const unsigned short* gB0 = Wb + (size_t)(n0 + (t >> 2)) * K + (t & 3) * 8;
  const unsigned short* gB1 = Wb + (size_t)(n0 + 64 + (t >> 2)) * K + (t & 3) * 8;
  unsigned short* lA0 = sA + (size_t)(wave * 64) * 8;
  unsigned short* lA1 = sA + (size_t)(256 + wave * 64) * 8;
  unsigned short* lB0 = sB + (size_t)(wave * 64) * 8;
  unsigned short* lB1 = sB + (size_t)(256 + wave * 64) * 8;

  const int rrow = lane & 15;
  const int rk = (lane >> 4) * 8;

  for (int k0 = 0; k0 < K; k0 += 32) {
    gload_lds16(gA0 + k0, lA0);
    gload_lds16(gA1 + k0, lA1);
    gload_lds16(gB0 + k0, lB0);
    gload_lds16(gB1 + k0, lB1);
    __syncthreads();
    bf16x8 af[4], bfr[4];
#pragma unroll
    for (int m = 0; m < 4; ++m)
      af[m] = *(const bf16x8*)&sA[(size_t)(wr * 64 + m * 16 + rrow) * 32 + rk];
#pragma unroll
    for (int n = 0; n < 4; ++n)
      bfr[n] = *(const bf16x8*)&sB[(size_t)(wc * 64 + n * 16 + rrow) * 32 + rk];
#pragma unroll
    for (int m = 0; m < 4; ++m)
#pragma unroll
      for (int n = 0; n < 4; ++n)
        acc[m][n] = __builtin_amdgcn_mfma_f32_16x16x32_bf16(af[m], bfr[n], acc[m][n], 0, 0, 0);
    __syncthreads();
  }
  const int crow0 = (lane >> 4) * 4;
  const int ccol = lane & 15;
#pragma unroll
  for (int n = 0; n < 4; ++n) {
    int col = n0 + wc * 64 + n * 16 + ccol;
    float bv = bias[col];
#pragma unroll
    for (int m = 0; m < 4; ++m) {
      int row = m0 + wr * 64 + m * 16 + crow0;
      float* cp = C + (size_t)row * N + col;
#pragma unroll
      for (int r = 0; r < 4; ++r) cp[(size_t)r * N] = acc[m][n][r] + bv;
    }
  }
}

// ---------------- fp32 fallback ----------------
__global__ __launch_bounds__(64) void lora_h_kernel(const float* __restrict__ x,
                                                    const float* __restrict__ A,
                                                    float* __restrict__ h,
                                                    float scale, int K, int R) {
  int m = blockIdx.x, lane = threadIdx.x;
  float acc[16];
#pragma unroll
  for (int r = 0; r < 16; ++r) acc[r] = 0.f;
  for (int d = lane; d < K; d += 64) {
    float xv = x[(size_t)m * K + d];
    for (int r = 0; r < R; ++r) acc[r] += xv * A[(size_t)r * K + d];
  }
  for (int off = 32; off; off >>= 1)
    for (int r = 0; r < R; ++r) acc[r] += __shfl_down(acc[r], off);
  if (lane == 0)
    for (int r = 0; r < R; ++r) h[(size_t)m * R + r] = acc[r] * scale;
}

__global__ __launch_bounds__(256) void fgemm_fallback(const float* __restrict__ X,
                                                      const float* __restrict__ W,
                                                      const float* __restrict__ Bm,
                                                      const float* __restrict__ bias,
                                                      const float* __restrict__ h,
                                                      float* __restrict__ C,
                                                      int M, int N, int K, int R) {
  __shared__ float sX[64][20];
  __shared__ float sW[64][20];
  int nt = N >> 6;
  int bx = blockIdx.x % nt, by = blockIdx.x / nt;
  int m0 = by << 6, n0 = bx << 6;
  int t = threadIdx.x;
  int tx = t & 15, ty = t >> 4;
  float acc[4][4] = {};
  int lr = t >> 2, lc = (t & 3) << 2;
  for (int k0 = 0; k0 < K; k0 += 16) {
    *(float4*)&sX[lr][lc] = *(const float4*)&X[(size_t)(m0 + lr) * K + k0 + lc];
    *(float4*)&sW[lr][lc] = *(const float4*)&W[(size_t)(n0 + lr) * K + k0 + lc];
    __syncthreads();
#pragma unroll
    for (int kk = 0; kk < 16; ++kk) {
      float a[4], b[4];
#pragma unroll
      for (int i = 0; i < 4; ++i) a[i] = sX[ty * 4 + i][kk];
#pragma unroll
      for (int j = 0; j < 4; ++j) b[j] = sW[tx * 4 + j][kk];
#pragma unroll
      for (int i = 0; i < 4; ++i)
#pragma unroll
        for (int j = 0; j < 4; ++j) acc[i][j] += a[i] * b[j];
    }
    __syncthreads();
  }
#pragma unroll
  for (int i = 0; i < 4; ++i) {
    int row = m0 + ty * 4 + i;
#pragma unroll
    for (int j = 0; j < 4; ++j) {
      int col = n0 + tx * 4 + j;
      float lo = 0.f;
      for (int r = 0; r < R; ++r) lo += h[(size_t)row * R + r] * Bm[(size_t)col * R + r];
      C[(size_t)row * N + col] = acc[i][j] + bias[col] + lo;
    }
  }
}

extern "C" void kernel_launch(void* const* d_in, const int* in_sizes, int n_in,
                              void* d_out, int out_size, void* d_ws, size_t ws_size,
                              hipStream_t stream) {
  const float* x    = (const float*)d_in[0];
  const float* W    = (const float*)d_in[1];
  const float* A    = (const float*)d_in[2];
  const float* Bm   = (const float*)d_in[3];
  const float* bias = (const float*)d_in[4];
  float* out = (float*)d_out;

  const int N = in_sizes[4];
  const int R = in_sizes[3] / N;
  const int K = in_sizes[2] / R;
  const int M = in_sizes[0] / K;
  const float scale = 16.0f / (float)R;

  const size_t xbytes = (size_t)M * K * 2;
  const size_t wbytes = (size_t)N * K * 2;
  const bool ws_ok = (ws_size >= xbytes + wbytes);
  const bool fast256 = ws_ok && (M % 256 == 0) && (N % 256 == 0) && (K % 64 == 0) && (K >= 128);
  const bool fast128 = ws_ok && (M % 128 == 0) && (N % 128 == 0) && (K % 32 == 0);

  if (fast256 || fast128) {
    unsigned short* xb = (unsigned short*)d_ws;
    unsigned short* wb = (unsigned short*)((char*)d_ws + xbytes);
    int n8 = M * K / 8;
    int t8 = N * K / 8;
    int total = n8 + t8;
    prep_kernel<<<dim3((total + 255) / 256), dim3(256), 0, stream>>>(x, W, A, Bm, xb, wb,
                                                                     scale, K, R, n8, t8);
    if (fast256) {
      int grid = (M / 256) * (N / 256);
      gemm256_bt_bias<<<dim3(grid), dim3(512), 0, stream>>>(xb, wb, bias, out, M, N, K);
    } else {
      int grid = (M / 128) * (N / 128);
      gemm_bt_bias<<<dim3(grid), dim3(256), 0, stream>>>(xb, wb, bias, out, M, N, K);
    }
  } else {
    float* h = (float*)d_ws;
    lora_h_kernel<<<dim3(M), dim3(64), 0, stream>>>(x, A, h, scale, K, R);
    int grid = (M / 64) * (N / 64);
    fgemm_fallback<<<dim3(grid), dim3(256), 0, stream>>>(x, W, Bm, bias, h, out, M, N, K, R);
  }
}